// Round 12
// baseline (2832.554 us; speedup 1.0000x reference)
//
#include <hip/hip_runtime.h>
#include <hip/hip_bf16.h>
#include <math.h>

#define N_NODES 20000
#define FDIM 20
#define DDIM 256
#define HH 8
#define LL 3
#define SS 4
#define EE 320000

typedef __attribute__((ext_vector_type(8))) short bf16x8;
typedef __attribute__((ext_vector_type(8))) unsigned short u16x8;
typedef __attribute__((ext_vector_type(4))) float f32x4;

__device__ inline unsigned short f2bf(float f) {
  unsigned u = __float_as_uint(f);
  unsigned r = u + 0x7FFFu + ((u >> 16) & 1u);
  return (unsigned short)(r >> 16);
}
__device__ inline float bf2f(unsigned short u) {
  return __uint_as_float(((unsigned)u) << 16);
}

// ---- f32 GEMM (x@in_w, K=20): C = A@B + bias (f32 out) ----
__global__ __launch_bounds__(256) void gemm_f32_kernel(
    const float* __restrict__ A, const float* __restrict__ B,
    const float* __restrict__ bias, float* __restrict__ C,
    int M, int Nc, int K)
{
  __shared__ float As[16][65];
  __shared__ float Bs[16][65];
  const int tid = threadIdx.x;
  const int tx = tid & 15, ty = tid >> 4;
  const int row0 = blockIdx.y * 64, col0 = blockIdx.x * 64;
  const int am = tid >> 2, ak = (tid & 3) * 4;
  const int bk = tid >> 4, bc = (tid & 15) * 4;
  float acc[4][4] = {};
  for (int k0 = 0; k0 < K; k0 += 16) {
    float4 av = make_float4(0.f, 0.f, 0.f, 0.f);
    int garow = row0 + am;
    if (garow < M) {
      if (k0 + ak + 3 < K) {
        av = *(const float4*)(A + (size_t)garow * K + k0 + ak);
      } else {
        float t[4];
        #pragma unroll
        for (int j = 0; j < 4; j++)
          t[j] = (k0 + ak + j < K) ? A[(size_t)garow * K + k0 + ak + j] : 0.f;
        av = make_float4(t[0], t[1], t[2], t[3]);
      }
    }
    As[ak + 0][am] = av.x; As[ak + 1][am] = av.y;
    As[ak + 2][am] = av.z; As[ak + 3][am] = av.w;
    float4 bv = make_float4(0.f, 0.f, 0.f, 0.f);
    if (k0 + bk < K)
      bv = *(const float4*)(B + (size_t)(k0 + bk) * Nc + col0 + bc);
    Bs[bk][bc + 0] = bv.x; Bs[bk][bc + 1] = bv.y;
    Bs[bk][bc + 2] = bv.z; Bs[bk][bc + 3] = bv.w;
    __syncthreads();
    #pragma unroll
    for (int kk = 0; kk < 16; kk++) {
      float a[4], b[4];
      #pragma unroll
      for (int i = 0; i < 4; i++) a[i] = As[kk][ty * 4 + i];
      #pragma unroll
      for (int j = 0; j < 4; j++) b[j] = Bs[kk][tx * 4 + j];
      #pragma unroll
      for (int i = 0; i < 4; i++)
        #pragma unroll
        for (int j = 0; j < 4; j++)
          acc[i][j] = fmaf(a[i], b[j], acc[i][j]);
    }
    __syncthreads();
  }
  #pragma unroll
  for (int i = 0; i < 4; i++) {
    int row = row0 + ty * 4 + i;
    if (row >= M) continue;
    int col = col0 + tx * 4;
    float4 v;
    float* vp = &v.x;
    #pragma unroll
    for (int j = 0; j < 4; j++) vp[j] = acc[i][j] + bias[col + j];
    *(float4*)(C + (size_t)row * Nc + col) = v;
  }
}

// ---- bf16 MFMA GEMM, 64x128 tile, 4 waves, BK=64, depth-1 dbuf LDS ----
// Halved barrier density vs BK=32: 16 MFMA/wave between barriers.
template<int ACT>
__global__ __launch_bounds__(256) void mfma_gemm64(
    const unsigned short* __restrict__ A, const unsigned short* __restrict__ BT,
    const float* __restrict__ bias, unsigned short* __restrict__ Cb,
    int ldc, int M, int K, int ldb)
{
  __shared__ unsigned short As[2][64][72];    // 64-K rows + 8 pad
  __shared__ unsigned short Bs[2][128][72];
  const int tid = threadIdx.x, lane = tid & 63, wid = tid >> 6;
  const int wr = (wid >> 1) * 32, wc = (wid & 1) * 64;
  const int row0 = blockIdx.y * 64, col0 = blockIdx.x * 128;
  const int sr = tid >> 2, sc = (tid & 3) * 16;
  const int c15 = lane & 15, g16 = lane >> 4;
  const int KT = K >> 6;
  f32x4 acc[2][4] = {};
  u16x8 a0, a1, b00, b01, b10, b11;
  int garow = row0 + sr; if (garow > M - 1) garow = M - 1;
  const unsigned short* Aptr = A + (size_t)garow * K + sc;
  const unsigned short* Bptr0 = BT + (size_t)(col0 + sr) * ldb + sc;
  const unsigned short* Bptr1 = BT + (size_t)(col0 + 64 + sr) * ldb + sc;

#define LD64(k0) { a0 = *(const u16x8*)(Aptr + (k0));  a1 = *(const u16x8*)(Aptr + (k0) + 8); \
  b00 = *(const u16x8*)(Bptr0 + (k0)); b01 = *(const u16x8*)(Bptr0 + (k0) + 8); \
  b10 = *(const u16x8*)(Bptr1 + (k0)); b11 = *(const u16x8*)(Bptr1 + (k0) + 8); }
#define WR64(buf) { *(u16x8*)&As[buf][sr][sc] = a0; *(u16x8*)&As[buf][sr][sc + 8] = a1; \
  *(u16x8*)&Bs[buf][sr][sc] = b00; *(u16x8*)&Bs[buf][sr][sc + 8] = b01; \
  *(u16x8*)&Bs[buf][64 + sr][sc] = b10; *(u16x8*)&Bs[buf][64 + sr][sc + 8] = b11; }
#define MM64(buf) { _Pragma("unroll") for (int ks = 0; ks < 2; ks++) { \
  bf16x8 af[2], bfv[4]; \
  _Pragma("unroll") for (int mi = 0; mi < 2; mi++) \
    af[mi] = *(const bf16x8*)&As[buf][wr + mi * 16 + c15][ks * 32 + g16 * 8]; \
  _Pragma("unroll") for (int ni = 0; ni < 4; ni++) \
    bfv[ni] = *(const bf16x8*)&Bs[buf][wc + ni * 16 + c15][ks * 32 + g16 * 8]; \
  _Pragma("unroll") for (int mi = 0; mi < 2; mi++) \
  _Pragma("unroll") for (int ni = 0; ni < 4; ni++) \
    acc[mi][ni] = __builtin_amdgcn_mfma_f32_16x16x32_bf16(af[mi], bfv[ni], acc[mi][ni], 0, 0, 0); } }

  LD64(0);
  WR64(0);
  __syncthreads();
  for (int kt = 0; kt < KT; kt++) {
    const int cur = kt & 1;
    if (kt + 1 < KT) LD64((kt + 1) << 6);
    MM64(cur);
    if (kt + 1 < KT) WR64(1 - cur);
    __syncthreads();
  }
#undef LD64
#undef WR64
#undef MM64
  #pragma unroll
  for (int mi = 0; mi < 2; mi++) {
    #pragma unroll
    for (int ni = 0; ni < 4; ni++) {
      int col = col0 + wc + ni * 16 + c15;
      float bval = bias ? bias[col] : 0.f;
      #pragma unroll
      for (int j = 0; j < 4; j++) {
        int row = row0 + wr + mi * 16 + g16 * 4 + j;
        if (row < M) {
          float t = acc[mi][ni][j] + bval;
          if (ACT == 1) t = 0.5f * t * (1.f + erff(t * 0.7071067811865475f));
          Cb[(size_t)row * ldc + col] = f2bf(t);
        }
      }
    }
  }
}

// ---- fused GEMM (+bias +resid) [+LN], 32x256, BK=32 depth-1 dbuf (unchanged) ----
template<int KTILES, int DO_LN, int ACCUM>
__global__ __launch_bounds__(256) void gemm_ln_kernel(
    const unsigned short* __restrict__ A, const unsigned short* __restrict__ BT,
    const float* __restrict__ bias, const float* __restrict__ resid,
    const float* __restrict__ gv, const float* __restrict__ bv,
    float* __restrict__ outf, unsigned short* __restrict__ outb,
    int M, int ldb, int bk0)
{
  constexpr int K = KTILES * 32;
  __shared__ unsigned short As[2][32][40];
  __shared__ unsigned short Bs[2][256][40];
  __shared__ float red[32][4][2];
  __shared__ float stats[32][2];
  const int tid = threadIdx.x, lane = tid & 63, w = tid >> 6;
  const int row0 = blockIdx.x * 32;
  const int sr2 = tid >> 3, sc2 = (tid & 7) * 4;
  const int sr = tid >> 2, sc = (tid & 3) * 8;
  const int g16 = lane >> 4, c15 = lane & 15;
  f32x4 acc[2][4] = {};
  ushort4 areg;
  u16x8 breg[4];
  int garow = row0 + sr2; if (garow > M - 1) garow = M - 1;
  const unsigned short* Aptr = A + (size_t)garow * K + sc2;
  const unsigned short* Bptr[4];
  #pragma unroll
  for (int p = 0; p < 4; p++)
    Bptr[p] = BT + (size_t)(p * 64 + sr) * ldb + bk0 + sc;

  areg = *(const ushort4*)(Aptr);
  #pragma unroll
  for (int p = 0; p < 4; p++) breg[p] = *(const u16x8*)(Bptr[p]);
  *(ushort4*)&As[0][sr2][sc2] = areg;
  #pragma unroll
  for (int p = 0; p < 4; p++) *(u16x8*)&Bs[0][p * 64 + sr][sc] = breg[p];
  __syncthreads();

  for (int kt = 0; kt < KTILES; kt++) {
    const int cur = kt & 1;
    if (kt + 1 < KTILES) {
      int k0 = (kt + 1) << 5;
      areg = *(const ushort4*)(Aptr + k0);
      #pragma unroll
      for (int p = 0; p < 4; p++) breg[p] = *(const u16x8*)(Bptr[p] + k0);
    }
    bf16x8 af[2], bfv[4];
    #pragma unroll
    for (int mi = 0; mi < 2; mi++)
      af[mi] = *(const bf16x8*)&As[cur][mi * 16 + c15][g16 * 8];
    #pragma unroll
    for (int ni = 0; ni < 4; ni++)
      bfv[ni] = *(const bf16x8*)&Bs[cur][w * 64 + ni * 16 + c15][g16 * 8];
    #pragma unroll
    for (int mi = 0; mi < 2; mi++)
      #pragma unroll
      for (int ni = 0; ni < 4; ni++)
        acc[mi][ni] = __builtin_amdgcn_mfma_f32_16x16x32_bf16(af[mi], bfv[ni], acc[mi][ni], 0, 0, 0);
    if (kt + 1 < KTILES) {
      *(ushort4*)&As[1 - cur][sr2][sc2] = areg;
      #pragma unroll
      for (int p = 0; p < 4; p++) *(u16x8*)&Bs[1 - cur][p * 64 + sr][sc] = breg[p];
    }
    __syncthreads();
  }
  // epilogue: bias / residual / accum
  #pragma unroll
  for (int mi = 0; mi < 2; mi++)
    #pragma unroll
    for (int ni = 0; ni < 4; ni++) {
      int col = w * 64 + ni * 16 + c15;
      float bval = bias ? bias[col] : 0.f;
      #pragma unroll
      for (int j = 0; j < 4; j++) {
        int row = row0 + mi * 16 + g16 * 4 + j;
        float t = acc[mi][ni][j] + bval;
        if (row < M) {
          if (DO_LN) t += resid[(size_t)row * DDIM + col];
          if (ACCUM) t += outf[(size_t)row * DDIM + col];
        }
        acc[mi][ni][j] = t;
      }
    }
  if (DO_LN) {
    #pragma unroll
    for (int mi = 0; mi < 2; mi++)
      #pragma unroll
      for (int j = 0; j < 4; j++) {
        float s = 0.f, q = 0.f;
        #pragma unroll
        for (int ni = 0; ni < 4; ni++) { float t = acc[mi][ni][j]; s += t; q += t * t; }
        #pragma unroll
        for (int d = 1; d < 16; d <<= 1) { s += __shfl_xor(s, d); q += __shfl_xor(q, d); }
        if (c15 == 0) {
          int r = mi * 16 + g16 * 4 + j;
          red[r][w][0] = s; red[r][w][1] = q;
        }
      }
    __syncthreads();
    if (tid < 32) {
      float s = red[tid][0][0] + red[tid][1][0] + red[tid][2][0] + red[tid][3][0];
      float q = red[tid][0][1] + red[tid][1][1] + red[tid][2][1] + red[tid][3][1];
      float mu = s * (1.f / DDIM);
      float var = q * (1.f / DDIM) - mu * mu;
      stats[tid][0] = mu;
      stats[tid][1] = rsqrtf(var + 1e-5f);
    }
    __syncthreads();
  }
  #pragma unroll
  for (int mi = 0; mi < 2; mi++)
    #pragma unroll
    for (int ni = 0; ni < 4; ni++) {
      int col = w * 64 + ni * 16 + c15;
      #pragma unroll
      for (int j = 0; j < 4; j++) {
        int r = mi * 16 + g16 * 4 + j;
        int row = row0 + r;
        if (row >= M) continue;
        float t = acc[mi][ni][j];
        float o = DO_LN ? (t - stats[r][0]) * stats[r][1] * gv[col] + bv[col] : t;
        outf[(size_t)row * DDIM + col] = o;
        if (DO_LN) outb[(size_t)row * DDIM + col] = f2bf(o);
      }
    }
}

// ---- tiled coalesced transpose f32 -> bf16 ----
__global__ __launch_bounds__(256) void transpose_bf16_tiled(
    const float* __restrict__ W, unsigned short* __restrict__ WT,
    int K, int Nn, int ldo, size_t istr, size_t ostr)
{
  __shared__ unsigned short t[64][65];
  const float* src = W + blockIdx.z * istr;
  unsigned short* dst = WT + blockIdx.z * ostr;
  int tid = threadIdx.x;
  int ty = tid >> 4, tx = tid & 15;
  int k0 = blockIdx.y * 64, n0 = blockIdx.x * 64;
  #pragma unroll
  for (int r = 0; r < 4; r++) {
    int k = k0 + r * 16 + ty;
    float4 v = *(const float4*)(src + (size_t)k * Nn + n0 + tx * 4);
    t[tx * 4 + 0][r * 16 + ty] = f2bf(v.x);
    t[tx * 4 + 1][r * 16 + ty] = f2bf(v.y);
    t[tx * 4 + 2][r * 16 + ty] = f2bf(v.z);
    t[tx * 4 + 3][r * 16 + ty] = f2bf(v.w);
  }
  __syncthreads();
  #pragma unroll
  for (int r = 0; r < 4; r++) {
    int n = r * 16 + ty;
    ushort4 o;
    o.x = t[n][tx * 4 + 0]; o.y = t[n][tx * 4 + 1];
    o.z = t[n][tx * 4 + 2]; o.w = t[n][tx * 4 + 3];
    *(ushort4*)(dst + (size_t)(n0 + n) * ldo + k0 + tx * 4) = o;
  }
}

// ---- helpers ----
__global__ void ifill_kernel(int* __restrict__ p, int v, int n) {
  int i = blockIdx.x * blockDim.x + threadIdx.x;
  if (i < n) p[i] = v;
}

__global__ void add_emb_dual(const float* __restrict__ base, const float* __restrict__ se,
                             float* __restrict__ h, unsigned short* __restrict__ hb) {
  int i4 = blockIdx.x * blockDim.x + threadIdx.x;
  if (i4 >= N_NODES * 64) return;
  float4 v = ((const float4*)base)[i4];
  float4 e = ((const float4*)se)[i4 & 63];
  v.x += e.x; v.y += e.y; v.z += e.z; v.w += e.w;
  ((float4*)h)[i4] = v;
  ushort4 o;
  o.x = f2bf(v.x); o.y = f2bf(v.y); o.z = f2bf(v.z); o.w = f2bf(v.w);
  ((ushort4*)hb)[i4] = o;
}

// ---- CSR build, batched over 4 stages via blockIdx.z ----
__global__ void hist_kernel(const int* __restrict__ ei, int* __restrict__ deg4) {
  int z = blockIdx.z;
  const int* dst = ei + (size_t)z * 2 * EE + EE;
  int* deg = deg4 + z * N_NODES;
  int e = blockIdx.x * blockDim.x + threadIdx.x;
  if (e < EE) atomicAdd(&deg[dst[e]], 1);
}

__global__ __launch_bounds__(1024) void scan_kernel(const int* __restrict__ deg4,
                                                    int* __restrict__ rowptr4) {
  int z = blockIdx.z;
  const int* deg = deg4 + z * N_NODES;
  int* rowptr = rowptr4 + z * (N_NODES + 1);
  __shared__ int part[1024];
  const int t = threadIdx.x;
  const int CH = (N_NODES + 1023) / 1024;
  int base = t * CH, s = 0;
  for (int i = 0; i < CH; i++) {
    int idx = base + i;
    if (idx < N_NODES) s += deg[idx];
  }
  part[t] = s;
  __syncthreads();
  for (int off = 1; off < 1024; off <<= 1) {
    int v = (t >= off) ? part[t - off] : 0;
    __syncthreads();
    part[t] += v;
    __syncthreads();
  }
  int run = (t == 0) ? 0 : part[t - 1];
  for (int i = 0; i < CH; i++) {
    int idx = base + i;
    if (idx < N_NODES) { rowptr[idx] = run; run += deg[idx]; }
  }
  if (t == 1023) rowptr[N_NODES] = run;
}

__global__ void csrfill_kernel(const int* __restrict__ ei,
                               const int* __restrict__ scm, const float* __restrict__ fcw,
                               const int* __restrict__ rowptr4, int* __restrict__ cur4,
                               int2* __restrict__ epe4) {
  int z = blockIdx.z;
  const int* src = ei + (size_t)z * 2 * EE;
  const int* dst = src + EE;
  const int* sc = scm + (size_t)z * EE;
  const float* fw = fcw + (size_t)z * EE;
  const int* rowptr = rowptr4 + z * (N_NODES + 1);
  int* cur = cur4 + z * N_NODES;
  int2* epe = epe4 + (size_t)z * EE;
  int e = blockIdx.x * blockDim.x + threadIdx.x;
  if (e >= EE) return;
  int d = dst[e];
  int slot = rowptr[d] + atomicAdd(&cur[d], 1);
  epe[slot] = make_int2(src[e] | (sc[e] << 31), __float_as_int(fw[e]));
}

// ---- fused edge attention + aggregation: wave-per-node, no online max ----
__global__ __launch_bounds__(256) void attn_agg_kernel(
    const unsigned short* __restrict__ QKV,
    const int* __restrict__ rowptr, const int2* __restrict__ epe,
    const float* __restrict__ lam, int l,
    unsigned short* __restrict__ agg)
{
  int node = blockIdx.x * 4 + (threadIdx.x >> 6);
  int lane = threadIdx.x & 63;
  if (node >= N_NODES) return;
  const float laml = lam[l];
  ushort4 q4 = *(const ushort4*)(QKV + (size_t)node * 768 + lane * 4);
  float qx = bf2f(q4.x), qy = bf2f(q4.y), qz = bf2f(q4.z), qw = bf2f(q4.w);
  int beg = rowptr[node], end = rowptr[node + 1];
  float ss = 0.f;
  float a0 = 0.f, a1 = 0.f, a2 = 0.f, a3 = 0.f;
  int i = beg;
  for (; i + 3 < end; i += 4) {
    int2 e0 = epe[i], e1 = epe[i + 1], e2 = epe[i + 2], e3 = epe[i + 3];
    const unsigned short* kp0 = QKV + (size_t)(e0.x & 0x7FFFFFFF) * 768 + 256 + lane * 4;
    const unsigned short* kp1 = QKV + (size_t)(e1.x & 0x7FFFFFFF) * 768 + 256 + lane * 4;
    const unsigned short* kp2 = QKV + (size_t)(e2.x & 0x7FFFFFFF) * 768 + 256 + lane * 4;
    const unsigned short* kp3 = QKV + (size_t)(e3.x & 0x7FFFFFFF) * 768 + 256 + lane * 4;
    ushort4 k0 = *(const ushort4*)kp0, v0 = *(const ushort4*)(kp0 + 256);
    ushort4 k1 = *(const ushort4*)kp1, v1 = *(const ushort4*)(kp1 + 256);
    ushort4 k2 = *(const ushort4*)kp2, v2 = *(const ushort4*)(kp2 + 256);
    ushort4 k3 = *(const ushort4*)kp3, v3 = *(const ushort4*)(kp3 + 256);
    float d0 = qx * bf2f(k0.x) + qy * bf2f(k0.y) + qz * bf2f(k0.z) + qw * bf2f(k0.w);
    float d1 = qx * bf2f(k1.x) + qy * bf2f(k1.y) + qz * bf2f(k1.z) + qw * bf2f(k1.w);
    float d2 = qx * bf2f(k2.x) + qy * bf2f(k2.y) + qz * bf2f(k2.z) + qw * bf2f(k2.w);
    float d3 = qx * bf2f(k3.x) + qy * bf2f(k3.y) + qz * bf2f(k3.z) + qw * bf2f(k3.w);
    d0 += __shfl_xor(d0, 1); d1 += __shfl_xor(d1, 1); d2 += __shfl_xor(d2, 1); d3 += __shfl_xor(d3, 1);
    d0 += __shfl_xor(d0, 2); d1 += __shfl_xor(d1, 2); d2 += __shfl_xor(d2, 2); d3 += __shfl_xor(d3, 2);
    d0 += __shfl_xor(d0, 4); d1 += __shfl_xor(d1, 4); d2 += __shfl_xor(d2, 4); d3 += __shfl_xor(d3, 4);
    float s0 = d0 * 0.17677669529663687f * (float)(((unsigned)e0.x) >> 31) + laml * __int_as_float(e0.y);
    float s1 = d1 * 0.17677669529663687f * (float)(((unsigned)e1.x) >> 31) + laml * __int_as_float(e1.y);
    float s2 = d2 * 0.17677669529663687f * (float)(((unsigned)e2.x) >> 31) + laml * __int_as_float(e2.y);
    float s3 = d3 * 0.17677669529663687f * (float)(((unsigned)e3.x) >> 31) + laml * __int_as_float(e3.y);
    float p0 = __expf(s0), p1 = __expf(s1), p2 = __expf(s2), p3 = __expf(s3);
    ss += (p0 + p1) + (p2 + p3);
    a0 += p0 * bf2f(v0.x) + p1 * bf2f(v1.x) + p2 * bf2f(v2.x) + p3 * bf2f(v3.x);
    a1 += p0 * bf2f(v0.y) + p1 * bf2f(v1.y) + p2 * bf2f(v2.y) + p3 * bf2f(v3.y);
    a2 += p0 * bf2f(v0.z) + p1 * bf2f(v1.z) + p2 * bf2f(v2.z) + p3 * bf2f(v3.z);
    a3 += p0 * bf2f(v0.w) + p1 * bf2f(v1.w) + p2 * bf2f(v2.w) + p3 * bf2f(v3.w);
  }
  for (; i < end; i++) {
    int2 ea = epe[i];
    const unsigned short* kpa = QKV + (size_t)(ea.x & 0x7FFFFFFF) * 768 + 256 + lane * 4;
    ushort4 ka = *(const ushort4*)kpa;
    ushort4 va = *(const ushort4*)(kpa + 256);
    float da = qx * bf2f(ka.x) + qy * bf2f(ka.y) + qz * bf2f(ka.z) + qw * bf2f(ka.w);
    da += __shfl_xor(da, 1);
    da += __shfl_xor(da, 2);
    da += __shfl_xor(da, 4);
    float s0 = da * 0.17677669529663687f * (float)(((unsigned)ea.x) >> 31) + laml * __int_as_float(ea.y);
    float p0 = __expf(s0);
    ss += p0;
    a0 += p0 * bf2f(va.x);
    a1 += p0 * bf2f(va.y);
    a2 += p0 * bf2f(va.z);
    a3 += p0 * bf2f(va.w);
  }
  float inv = 1.f / (ss + 1e-16f);
  ushort4 o;
  o.x = f2bf(a0 * inv); o.y = f2bf(a1 * inv);
  o.z = f2bf(a2 * inv); o.w = f2bf(a3 * inv);
  *(ushort4*)(agg + (size_t)node * DDIM + lane * 4) = o;
}

// ---- standalone LayerNorm (final output only) ----
__global__ __launch_bounds__(256) void ln_kernel(
    const float* __restrict__ X, const float* __restrict__ g,
    const float* __restrict__ b, float* __restrict__ out, int M)
{
  int row = blockIdx.x * (blockDim.x >> 6) + (threadIdx.x >> 6);
  int lane = threadIdx.x & 63;
  if (row >= M) return;
  float4 x = ((const float4*)(X + (size_t)row * DDIM))[lane];
  float s = x.x + x.y + x.z + x.w;
  #pragma unroll
  for (int mk = 1; mk < 64; mk <<= 1) s += __shfl_xor(s, mk);
  float mu = s * (1.f / DDIM);
  float d0 = x.x - mu, d1 = x.y - mu, d2 = x.z - mu, d3 = x.w - mu;
  float vs = d0 * d0 + d1 * d1 + d2 * d2 + d3 * d3;
  #pragma unroll
  for (int mk = 1; mk < 64; mk <<= 1) vs += __shfl_xor(vs, mk);
  float inv = rsqrtf(vs * (1.f / DDIM) + 1e-5f);
  float4 gg = ((const float4*)g)[lane];
  float4 bb = ((const float4*)b)[lane];
  float4 o;
  o.x = d0 * inv * gg.x + bb.x;
  o.y = d1 * inv * gg.y + bb.y;
  o.z = d2 * inv * gg.z + bb.z;
  o.w = d3 * inv * gg.w + bb.w;
  ((float4*)(out + (size_t)row * DDIM))[lane] = o;
}

// ---- host launch ----
extern "C" void kernel_launch(void* const* d_in, const int* in_sizes, int n_in,
                              void* d_out, int out_size, void* d_ws, size_t ws_size,
                              hipStream_t stream) {
  const float* x      = (const float*)d_in[0];
  const int*   ei     = (const int*)d_in[1];
  const int*   scm    = (const int*)d_in[2];
  const float* fcw    = (const float*)d_in[3];
  const float* in_w   = (const float*)d_in[4];
  const float* in_b   = (const float*)d_in[5];
  const float* st_emb = (const float*)d_in[6];
  const float* Wq     = (const float*)d_in[7];
  const float* Wk     = (const float*)d_in[8];
  const float* Wv     = (const float*)d_in[9];
  const float* Wo     = (const float*)d_in[10];
  const float* bo     = (const float*)d_in[11];
  const float* ln1g   = (const float*)d_in[12];
  const float* ln1b   = (const float*)d_in[13];
  const float* ln2g   = (const float*)d_in[14];
  const float* ln2b   = (const float*)d_in[15];
  const float* fw1    = (const float*)d_in[16];
  const float* fb1    = (const float*)d_in[17];
  const float* fw2    = (const float*)d_in[18];
  const float* fb2    = (const float*)d_in[19];
  const float* lam    = (const float*)d_in[20];
  const float* fus_w  = (const float*)d_in[21];
  const float* fus_b  = (const float*)d_in[22];
  const float* outg   = (const float*)d_in[23];
  const float* outb   = (const float*)d_in[24];

  const size_t ND = (size_t)N_NODES * DDIM;   // 5.12M
  const int DD = DDIM * DDIM;                  // 65536
  float* W = (float*)d_ws;
  size_t off = 0;
  auto alloc = [&](size_t n) { float* p = W + off; off += n; return p; };
  // union: f1 bf16 [N,1024] | QKV bf16 [N,768] interleaved
  float* u1 = alloc((size_t)N_NODES * 1024 / 2);
  unsigned short* f1  = (unsigned short*)u1;
  unsigned short* QKV = (unsigned short*)u1;
  unsigned short* aggb    = (unsigned short*)alloc(ND / 2);
  float* base = alloc(ND);
  float* h    = alloc(ND);
  float* out1 = alloc(ND);
  unsigned short* h_bf    = (unsigned short*)alloc(ND / 2);
  unsigned short* out1_bf = (unsigned short*)alloc(ND / 2);
  unsigned short* bfb = (unsigned short*)alloc(1310720);  // 2,621,440 shorts
  unsigned short* wqkvT = bfb;                   // 3 * 196608
  unsigned short* woT   = bfb + 589824;          // 3 * 65536
  unsigned short* fw1T  = bfb + 786432;          // 3 * 262144
  unsigned short* fw2T  = bfb + 1572864;         // 3 * 262144
  unsigned short* fusT  = bfb + 2359296;         // 262144
  int*  rowptr4 = (int*)alloc(4 * (N_NODES + 1) + 4);
  int*  deg4    = (int*)alloc(4 * N_NODES);
  int*  cur4    = (int*)alloc(4 * N_NODES);
  int2* epe4    = (int2*)alloc((size_t)4 * EE * 2);
  float* fus   = (float*)d_out;

  // ---- weights -> bf16 transposed ----
  transpose_bf16_tiled<<<dim3(4, 4, 3), 256, 0, stream>>>(Wq, wqkvT,           DDIM, DDIM, DDIM, DD, 196608);
  transpose_bf16_tiled<<<dim3(4, 4, 3), 256, 0, stream>>>(Wk, wqkvT + 65536,   DDIM, DDIM, DDIM, DD, 196608);
  transpose_bf16_tiled<<<dim3(4, 4, 3), 256, 0, stream>>>(Wv, wqkvT + 131072,  DDIM, DDIM, DDIM, DD, 196608);
  transpose_bf16_tiled<<<dim3(4, 4, 3), 256, 0, stream>>>(Wo, woT,             DDIM, DDIM, DDIM, DD, DD);
  transpose_bf16_tiled<<<dim3(16, 4, 3), 256, 0, stream>>>(fw1, fw1T, DDIM, 4 * DDIM, DDIM, 4 * DD, 4 * DD);
  transpose_bf16_tiled<<<dim3(4, 16, 3), 256, 0, stream>>>(fw2, fw2T, 4 * DDIM, DDIM, 4 * DDIM, 4 * DD, 4 * DD);
  transpose_bf16_tiled<<<dim3(4, 16, 1), 256, 0, stream>>>(fus_w, fusT, 4 * DDIM, DDIM, 4 * DDIM, 0, 0);

  // ---- CSR build for ALL 4 stages, once, batched on z ----
  const int eBlocks = (EE + 255) / 256;
  ifill_kernel<<<(8 * N_NODES + 255) / 256, 256, 0, stream>>>(deg4, 0, 8 * N_NODES);  // deg4+cur4
  hist_kernel<<<dim3(eBlocks, 1, 4), 256, 0, stream>>>(ei, deg4);
  scan_kernel<<<dim3(1, 1, 4), 1024, 0, stream>>>(deg4, rowptr4);
  csrfill_kernel<<<dim3(eBlocks, 1, 4), 256, 0, stream>>>(ei, scm, fcw, rowptr4, cur4, epe4);

  // base = x @ in_w + in_b (once)
  dim3 gF32(DDIM / 64, (N_NODES + 63) / 64);
  gemm_f32_kernel<<<gF32, 256, 0, stream>>>(x, in_w, in_b, base, N_NODES, DDIM, FDIM);

  const int lnBlocks = (N_NODES + 3) / 4;
  const int emBlocks = (N_NODES * 64 + 255) / 256;
  dim3 gQKV(6, (N_NODES + 63) / 64);   // 64x128 tiles
  dim3 gFFN1(8, (N_NODES + 63) / 64);
  const int fusedBlocks = (N_NODES + 31) / 32;   // 625

  for (int s = 0; s < SS; s++) {
    const int* rowptr = rowptr4 + s * (N_NODES + 1);
    const int2* epe = epe4 + (size_t)s * EE;

    // h = base + stage_emb[s]  (f32 + bf16)
    add_emb_dual<<<emBlocks, 256, 0, stream>>>(base, st_emb + s * DDIM, h, h_bf);

    for (int l = 0; l < LL; l++) {
      // fused QKV: [N,768] bf16 interleaved
      mfma_gemm64<0><<<gQKV, 256, 0, stream>>>(
          h_bf, wqkvT + (size_t)l * 196608, nullptr, QKV, 768, N_NODES, DDIM, DDIM);

      attn_agg_kernel<<<lnBlocks, 256, 0, stream>>>(QKV, rowptr, epe, lam, l, aggb);

      // Wo + bias + resid(h) + LN1 -> out1 (f32+bf16)
      gemm_ln_kernel<8, 1, 0><<<fusedBlocks, 256, 0, stream>>>(
          aggb, woT + (size_t)l * DD, bo + l * DDIM, h,
          ln1g + l * DDIM, ln1b + l * DDIM, out1, out1_bf, N_NODES, DDIM, 0);

      // FFN1 + gelu -> f1 bf16
      mfma_gemm64<1><<<gFFN1, 256, 0, stream>>>(
          out1_bf, fw1T + (size_t)l * 4 * DD, fb1 + l * 4 * DDIM, f1, 4 * DDIM,
          N_NODES, DDIM, DDIM);

      // FFN2 + bias + resid(out1) + LN2 -> h (f32+bf16)
      gemm_ln_kernel<32, 1, 0><<<fusedBlocks, 256, 0, stream>>>(
          f1, fw2T + (size_t)l * 4 * DD, fb2 + l * DDIM, out1,
          ln2g + l * DDIM, ln2b + l * DDIM, h, h_bf, N_NODES, 4 * DDIM, 0);
    }

    // fusion accumulate into d_out
    if (s == 0)
      gemm_ln_kernel<8, 0, 0><<<fusedBlocks, 256, 0, stream>>>(
          h_bf, fusT, fus_b, nullptr, nullptr, nullptr, fus, nullptr,
          N_NODES, 4 * DDIM, s * DDIM);
    else
      gemm_ln_kernel<8, 0, 1><<<fusedBlocks, 256, 0, stream>>>(
          h_bf, fusT, nullptr, nullptr, nullptr, nullptr, fus, nullptr,
          N_NODES, 4 * DDIM, s * DDIM);
  }

  // final LN in-place on d_out
  ln_kernel<<<lnBlocks, 256, 0, stream>>>(fus, outg, outb, (float*)d_out, N_NODES);
}

// Round 13
// 2488.702 us; speedup vs baseline: 1.1382x; 1.1382x over previous
//
#include <hip/hip_runtime.h>
#include <hip/hip_bf16.h>
#include <math.h>

#define N_NODES 20000
#define FDIM 20
#define DDIM 256
#define HH 8
#define LL 3
#define SS 4
#define EE 320000

typedef __attribute__((ext_vector_type(8))) short bf16x8;
typedef __attribute__((ext_vector_type(8))) unsigned short u16x8;
typedef __attribute__((ext_vector_type(4))) float f32x4;

__device__ inline unsigned short f2bf(float f) {
  unsigned u = __float_as_uint(f);
  unsigned r = u + 0x7FFFu + ((u >> 16) & 1u);
  return (unsigned short)(r >> 16);
}
__device__ inline float bf2f(unsigned short u) {
  return __uint_as_float(((unsigned)u) << 16);
}

// ---- f32 GEMM (x@in_w, K=20): C = A@B + bias (f32 out) ----
__global__ __launch_bounds__(256) void gemm_f32_kernel(
    const float* __restrict__ A, const float* __restrict__ B,
    const float* __restrict__ bias, float* __restrict__ C,
    int M, int Nc, int K)
{
  __shared__ float As[16][65];
  __shared__ float Bs[16][65];
  const int tid = threadIdx.x;
  const int tx = tid & 15, ty = tid >> 4;
  const int row0 = blockIdx.y * 64, col0 = blockIdx.x * 64;
  const int am = tid >> 2, ak = (tid & 3) * 4;
  const int bk = tid >> 4, bc = (tid & 15) * 4;
  float acc[4][4] = {};
  for (int k0 = 0; k0 < K; k0 += 16) {
    float4 av = make_float4(0.f, 0.f, 0.f, 0.f);
    int garow = row0 + am;
    if (garow < M) {
      if (k0 + ak + 3 < K) {
        av = *(const float4*)(A + (size_t)garow * K + k0 + ak);
      } else {
        float t[4];
        #pragma unroll
        for (int j = 0; j < 4; j++)
          t[j] = (k0 + ak + j < K) ? A[(size_t)garow * K + k0 + ak + j] : 0.f;
        av = make_float4(t[0], t[1], t[2], t[3]);
      }
    }
    As[ak + 0][am] = av.x; As[ak + 1][am] = av.y;
    As[ak + 2][am] = av.z; As[ak + 3][am] = av.w;
    float4 bv = make_float4(0.f, 0.f, 0.f, 0.f);
    if (k0 + bk < K)
      bv = *(const float4*)(B + (size_t)(k0 + bk) * Nc + col0 + bc);
    Bs[bk][bc + 0] = bv.x; Bs[bk][bc + 1] = bv.y;
    Bs[bk][bc + 2] = bv.z; Bs[bk][bc + 3] = bv.w;
    __syncthreads();
    #pragma unroll
    for (int kk = 0; kk < 16; kk++) {
      float a[4], b[4];
      #pragma unroll
      for (int i = 0; i < 4; i++) a[i] = As[kk][ty * 4 + i];
      #pragma unroll
      for (int j = 0; j < 4; j++) b[j] = Bs[kk][tx * 4 + j];
      #pragma unroll
      for (int i = 0; i < 4; i++)
        #pragma unroll
        for (int j = 0; j < 4; j++)
          acc[i][j] = fmaf(a[i], b[j], acc[i][j]);
    }
    __syncthreads();
  }
  #pragma unroll
  for (int i = 0; i < 4; i++) {
    int row = row0 + ty * 4 + i;
    if (row >= M) continue;
    int col = col0 + tx * 4;
    float4 v;
    float* vp = &v.x;
    #pragma unroll
    for (int j = 0; j < 4; j++) vp[j] = acc[i][j] + bias[col + j];
    *(float4*)(C + (size_t)row * Nc + col) = v;
  }
}

// ---- bf16 MFMA GEMM, 64x128 tile, 4 waves, BK=32, depth-1 dbuf LDS ----
// (empirically best: 68 VGPR, 30KB LDS, ~25% occupancy)
template<int ACT>
__global__ __launch_bounds__(256) void mfma_gemm64(
    const unsigned short* __restrict__ A, const unsigned short* __restrict__ BT,
    const float* __restrict__ bias, unsigned short* __restrict__ Cb,
    int ldc, int M, int K, int ldb)
{
  __shared__ unsigned short As[2][64][40];
  __shared__ unsigned short Bs[2][128][40];
  const int tid = threadIdx.x, lane = tid & 63, wid = tid >> 6;
  const int wr = (wid >> 1) * 32, wc = (wid & 1) * 64;
  const int row0 = blockIdx.y * 64, col0 = blockIdx.x * 128;
  const int sr = tid >> 2, sc = (tid & 3) * 8;
  const int c15 = lane & 15, g16 = lane >> 4;
  const int KT = K >> 5;
  f32x4 acc[2][4] = {};
  u16x8 areg, breg0, breg1;
  int garow = row0 + sr; if (garow > M - 1) garow = M - 1;
  const unsigned short* Aptr = A + (size_t)garow * K + sc;
  const unsigned short* Bptr0 = BT + (size_t)(col0 + sr) * ldb + sc;
  const unsigned short* Bptr1 = BT + (size_t)(col0 + 64 + sr) * ldb + sc;

  areg = *(const u16x8*)(Aptr);
  breg0 = *(const u16x8*)(Bptr0);
  breg1 = *(const u16x8*)(Bptr1);
  *(u16x8*)&As[0][sr][sc] = areg;
  *(u16x8*)&Bs[0][sr][sc] = breg0;
  *(u16x8*)&Bs[0][64 + sr][sc] = breg1;
  __syncthreads();

  for (int kt = 0; kt < KT; kt++) {
    const int cur = kt & 1;
    if (kt + 1 < KT) {
      int k0 = (kt + 1) << 5;
      areg = *(const u16x8*)(Aptr + k0);
      breg0 = *(const u16x8*)(Bptr0 + k0);
      breg1 = *(const u16x8*)(Bptr1 + k0);
    }
    bf16x8 af[2], bfv[4];
    #pragma unroll
    for (int mi = 0; mi < 2; mi++)
      af[mi] = *(const bf16x8*)&As[cur][wr + mi * 16 + c15][g16 * 8];
    #pragma unroll
    for (int ni = 0; ni < 4; ni++)
      bfv[ni] = *(const bf16x8*)&Bs[cur][wc + ni * 16 + c15][g16 * 8];
    #pragma unroll
    for (int mi = 0; mi < 2; mi++)
      #pragma unroll
      for (int ni = 0; ni < 4; ni++)
        acc[mi][ni] = __builtin_amdgcn_mfma_f32_16x16x32_bf16(af[mi], bfv[ni], acc[mi][ni], 0, 0, 0);
    if (kt + 1 < KT) {
      *(u16x8*)&As[1 - cur][sr][sc] = areg;
      *(u16x8*)&Bs[1 - cur][sr][sc] = breg0;
      *(u16x8*)&Bs[1 - cur][64 + sr][sc] = breg1;
    }
    __syncthreads();
  }
  #pragma unroll
  for (int mi = 0; mi < 2; mi++) {
    #pragma unroll
    for (int ni = 0; ni < 4; ni++) {
      int col = col0 + wc + ni * 16 + c15;
      float bval = bias ? bias[col] : 0.f;
      #pragma unroll
      for (int j = 0; j < 4; j++) {
        int row = row0 + wr + mi * 16 + g16 * 4 + j;
        if (row < M) {
          float t = acc[mi][ni][j] + bval;
          if (ACT == 1) t = 0.5f * t * (1.f + erff(t * 0.7071067811865475f));
          Cb[(size_t)row * ldc + col] = f2bf(t);
        }
      }
    }
  }
}

// ---- fused GEMM (+bias +resid) [+LN], 32x256, BK=32, depth-1 dbuf, 625 blocks ----
template<int KTILES, int DO_LN, int ACCUM>
__global__ __launch_bounds__(256) void gemm_ln_kernel(
    const unsigned short* __restrict__ A, const unsigned short* __restrict__ BT,
    const float* __restrict__ bias, const float* __restrict__ resid,
    const float* __restrict__ gv, const float* __restrict__ bv,
    float* __restrict__ outf, unsigned short* __restrict__ outb,
    int M, int ldb, int bk0)
{
  constexpr int K = KTILES * 32;
  __shared__ unsigned short As[2][32][40];
  __shared__ unsigned short Bs[2][256][40];
  __shared__ float red[32][4][2];
  __shared__ float stats[32][2];
  const int tid = threadIdx.x, lane = tid & 63, w = tid >> 6;
  const int row0 = blockIdx.x * 32;
  const int sr2 = tid >> 3, sc2 = (tid & 7) * 4;
  const int sr = tid >> 2, sc = (tid & 3) * 8;
  const int g16 = lane >> 4, c15 = lane & 15;
  f32x4 acc[2][4] = {};
  ushort4 areg;
  u16x8 breg[4];
  int garow = row0 + sr2; if (garow > M - 1) garow = M - 1;
  const unsigned short* Aptr = A + (size_t)garow * K + sc2;
  const unsigned short* Bptr[4];
  #pragma unroll
  for (int p = 0; p < 4; p++)
    Bptr[p] = BT + (size_t)(p * 64 + sr) * ldb + bk0 + sc;

  areg = *(const ushort4*)(Aptr);
  #pragma unroll
  for (int p = 0; p < 4; p++) breg[p] = *(const u16x8*)(Bptr[p]);
  *(ushort4*)&As[0][sr2][sc2] = areg;
  #pragma unroll
  for (int p = 0; p < 4; p++) *(u16x8*)&Bs[0][p * 64 + sr][sc] = breg[p];
  __syncthreads();

  for (int kt = 0; kt < KTILES; kt++) {
    const int cur = kt & 1;
    if (kt + 1 < KTILES) {
      int k0 = (kt + 1) << 5;
      areg = *(const ushort4*)(Aptr + k0);
      #pragma unroll
      for (int p = 0; p < 4; p++) breg[p] = *(const u16x8*)(Bptr[p] + k0);
    }
    bf16x8 af[2], bfv[4];
    #pragma unroll
    for (int mi = 0; mi < 2; mi++)
      af[mi] = *(const bf16x8*)&As[cur][mi * 16 + c15][g16 * 8];
    #pragma unroll
    for (int ni = 0; ni < 4; ni++)
      bfv[ni] = *(const bf16x8*)&Bs[cur][w * 64 + ni * 16 + c15][g16 * 8];
    #pragma unroll
    for (int mi = 0; mi < 2; mi++)
      #pragma unroll
      for (int ni = 0; ni < 4; ni++)
        acc[mi][ni] = __builtin_amdgcn_mfma_f32_16x16x32_bf16(af[mi], bfv[ni], acc[mi][ni], 0, 0, 0);
    if (kt + 1 < KTILES) {
      *(ushort4*)&As[1 - cur][sr2][sc2] = areg;
      #pragma unroll
      for (int p = 0; p < 4; p++) *(u16x8*)&Bs[1 - cur][p * 64 + sr][sc] = breg[p];
    }
    __syncthreads();
  }
  // epilogue: bias / residual / accum
  #pragma unroll
  for (int mi = 0; mi < 2; mi++)
    #pragma unroll
    for (int ni = 0; ni < 4; ni++) {
      int col = w * 64 + ni * 16 + c15;
      float bval = bias ? bias[col] : 0.f;
      #pragma unroll
      for (int j = 0; j < 4; j++) {
        int row = row0 + mi * 16 + g16 * 4 + j;
        float t = acc[mi][ni][j] + bval;
        if (row < M) {
          if (DO_LN) t += resid[(size_t)row * DDIM + col];
          if (ACCUM) t += outf[(size_t)row * DDIM + col];
        }
        acc[mi][ni][j] = t;
      }
    }
  if (DO_LN) {
    #pragma unroll
    for (int mi = 0; mi < 2; mi++)
      #pragma unroll
      for (int j = 0; j < 4; j++) {
        float s = 0.f, q = 0.f;
        #pragma unroll
        for (int ni = 0; ni < 4; ni++) { float t = acc[mi][ni][j]; s += t; q += t * t; }
        #pragma unroll
        for (int d = 1; d < 16; d <<= 1) { s += __shfl_xor(s, d); q += __shfl_xor(q, d); }
        if (c15 == 0) {
          int r = mi * 16 + g16 * 4 + j;
          red[r][w][0] = s; red[r][w][1] = q;
        }
      }
    __syncthreads();
    if (tid < 32) {
      float s = red[tid][0][0] + red[tid][1][0] + red[tid][2][0] + red[tid][3][0];
      float q = red[tid][0][1] + red[tid][1][1] + red[tid][2][1] + red[tid][3][1];
      float mu = s * (1.f / DDIM);
      float var = q * (1.f / DDIM) - mu * mu;
      stats[tid][0] = mu;
      stats[tid][1] = rsqrtf(var + 1e-5f);
    }
    __syncthreads();
  }
  #pragma unroll
  for (int mi = 0; mi < 2; mi++)
    #pragma unroll
    for (int ni = 0; ni < 4; ni++) {
      int col = w * 64 + ni * 16 + c15;
      #pragma unroll
      for (int j = 0; j < 4; j++) {
        int r = mi * 16 + g16 * 4 + j;
        int row = row0 + r;
        if (row >= M) continue;
        float t = acc[mi][ni][j];
        float o = DO_LN ? (t - stats[r][0]) * stats[r][1] * gv[col] + bv[col] : t;
        outf[(size_t)row * DDIM + col] = o;
        if (DO_LN) outb[(size_t)row * DDIM + col] = f2bf(o);
      }
    }
}

// ---- tiled coalesced transpose f32 -> bf16 (generic, z-batched) ----
__global__ __launch_bounds__(256) void transpose_bf16_tiled(
    const float* __restrict__ W, unsigned short* __restrict__ WT,
    int K, int Nn, int ldo, size_t istr, size_t ostr)
{
  __shared__ unsigned short t[64][65];
  const float* src = W + blockIdx.z * istr;
  unsigned short* dst = WT + blockIdx.z * ostr;
  int tid = threadIdx.x;
  int ty = tid >> 4, tx = tid & 15;
  int k0 = blockIdx.y * 64, n0 = blockIdx.x * 64;
  #pragma unroll
  for (int r = 0; r < 4; r++) {
    int k = k0 + r * 16 + ty;
    float4 v = *(const float4*)(src + (size_t)k * Nn + n0 + tx * 4);
    t[tx * 4 + 0][r * 16 + ty] = f2bf(v.x);
    t[tx * 4 + 1][r * 16 + ty] = f2bf(v.y);
    t[tx * 4 + 2][r * 16 + ty] = f2bf(v.z);
    t[tx * 4 + 3][r * 16 + ty] = f2bf(v.w);
  }
  __syncthreads();
  #pragma unroll
  for (int r = 0; r < 4; r++) {
    int n = r * 16 + ty;
    ushort4 o;
    o.x = t[n][tx * 4 + 0]; o.y = t[n][tx * 4 + 1];
    o.z = t[n][tx * 4 + 2]; o.w = t[n][tx * 4 + 3];
    *(ushort4*)(dst + (size_t)(n0 + n) * ldo + k0 + tx * 4) = o;
  }
}

// ---- batched 256x256 transpose for Wq/Wk/Wv/Wo (z = wi*3 + layer) ----
__global__ __launch_bounds__(256) void transpose_qkvo_kernel(
    const float* __restrict__ Wq, const float* __restrict__ Wk,
    const float* __restrict__ Wv, const float* __restrict__ Wo,
    unsigned short* __restrict__ wqkvT, unsigned short* __restrict__ woT)
{
  __shared__ unsigned short t[64][65];
  const int z = blockIdx.z;
  const int wi = z >> 2, l = z & 3;          // wi in [0,4) would need z=16; use z = wi*3+l
  (void)wi; (void)l;
  const int widx = z / 3, lay = z - widx * 3;
  const float* srcs[4] = { Wq, Wk, Wv, Wo };
  const float* src = srcs[widx] + (size_t)lay * 65536;
  unsigned short* dst = (widx < 3)
      ? wqkvT + (size_t)lay * 196608 + (size_t)widx * 65536
      : woT + (size_t)lay * 65536;
  int tid = threadIdx.x;
  int ty = tid >> 4, tx = tid & 15;
  int k0 = blockIdx.y * 64, n0 = blockIdx.x * 64;
  #pragma unroll
  for (int r = 0; r < 4; r++) {
    int k = k0 + r * 16 + ty;
    float4 v = *(const float4*)(src + (size_t)k * DDIM + n0 + tx * 4);
    t[tx * 4 + 0][r * 16 + ty] = f2bf(v.x);
    t[tx * 4 + 1][r * 16 + ty] = f2bf(v.y);
    t[tx * 4 + 2][r * 16 + ty] = f2bf(v.z);
    t[tx * 4 + 3][r * 16 + ty] = f2bf(v.w);
  }
  __syncthreads();
  #pragma unroll
  for (int r = 0; r < 4; r++) {
    int n = r * 16 + ty;
    ushort4 o;
    o.x = t[n][tx * 4 + 0]; o.y = t[n][tx * 4 + 1];
    o.z = t[n][tx * 4 + 2]; o.w = t[n][tx * 4 + 3];
    *(ushort4*)(dst + (size_t)(n0 + n) * DDIM + k0 + tx * 4) = o;
  }
}

// ---- helpers ----
__global__ void ifill_kernel(int* __restrict__ p, int v, int n) {
  int i = blockIdx.x * blockDim.x + threadIdx.x;
  if (i < n) p[i] = v;
}

__global__ void add_emb_dual(const float* __restrict__ base, const float* __restrict__ se,
                             float* __restrict__ h, unsigned short* __restrict__ hb) {
  int i4 = blockIdx.x * blockDim.x + threadIdx.x;
  if (i4 >= N_NODES * 64) return;
  float4 v = ((const float4*)base)[i4];
  float4 e = ((const float4*)se)[i4 & 63];
  v.x += e.x; v.y += e.y; v.z += e.z; v.w += e.w;
  ((float4*)h)[i4] = v;
  ushort4 o;
  o.x = f2bf(v.x); o.y = f2bf(v.y); o.z = f2bf(v.z); o.w = f2bf(v.w);
  ((ushort4*)hb)[i4] = o;
}

// ---- CSR build, batched over 4 stages via blockIdx.z ----
__global__ void hist_kernel(const int* __restrict__ ei, int* __restrict__ deg4) {
  int z = blockIdx.z;
  const int* dst = ei + (size_t)z * 2 * EE + EE;
  int* deg = deg4 + z * N_NODES;
  int e = blockIdx.x * blockDim.x + threadIdx.x;
  if (e < EE) atomicAdd(&deg[dst[e]], 1);
}

__global__ __launch_bounds__(1024) void scan_kernel(const int* __restrict__ deg4,
                                                    int* __restrict__ rowptr4) {
  int z = blockIdx.z;
  const int* deg = deg4 + z * N_NODES;
  int* rowptr = rowptr4 + z * (N_NODES + 1);
  __shared__ int part[1024];
  const int t = threadIdx.x;
  const int CH = (N_NODES + 1023) / 1024;
  int base = t * CH, s = 0;
  for (int i = 0; i < CH; i++) {
    int idx = base + i;
    if (idx < N_NODES) s += deg[idx];
  }
  part[t] = s;
  __syncthreads();
  for (int off = 1; off < 1024; off <<= 1) {
    int v = (t >= off) ? part[t - off] : 0;
    __syncthreads();
    part[t] += v;
    __syncthreads();
  }
  int run = (t == 0) ? 0 : part[t - 1];
  for (int i = 0; i < CH; i++) {
    int idx = base + i;
    if (idx < N_NODES) { rowptr[idx] = run; run += deg[idx]; }
  }
  if (t == 1023) rowptr[N_NODES] = run;
}

__global__ void csrfill_kernel(const int* __restrict__ ei,
                               const int* __restrict__ scm, const float* __restrict__ fcw,
                               const int* __restrict__ rowptr4, int* __restrict__ cur4,
                               int2* __restrict__ epe4) {
  int z = blockIdx.z;
  const int* src = ei + (size_t)z * 2 * EE;
  const int* dst = src + EE;
  const int* sc = scm + (size_t)z * EE;
  const float* fw = fcw + (size_t)z * EE;
  const int* rowptr = rowptr4 + z * (N_NODES + 1);
  int* cur = cur4 + z * N_NODES;
  int2* epe = epe4 + (size_t)z * EE;
  int e = blockIdx.x * blockDim.x + threadIdx.x;
  if (e >= EE) return;
  int d = dst[e];
  int slot = rowptr[d] + atomicAdd(&cur[d], 1);
  epe[slot] = make_int2(src[e] | (sc[e] << 31), __float_as_int(fw[e]));
}

// ---- fused edge attention + aggregation: wave-per-node, no online max ----
// softmax is shift-invariant; scores bounded (LN'd bf16 inputs) so raw
// expf is safe in f32 -> no loop-carried rescale chain.
__global__ __launch_bounds__(256) void attn_agg_kernel(
    const unsigned short* __restrict__ QKV,
    const int* __restrict__ rowptr, const int2* __restrict__ epe,
    const float* __restrict__ lam, int l,
    unsigned short* __restrict__ agg)
{
  int node = blockIdx.x * 4 + (threadIdx.x >> 6);
  int lane = threadIdx.x & 63;
  if (node >= N_NODES) return;
  const float laml = lam[l];
  ushort4 q4 = *(const ushort4*)(QKV + (size_t)node * 768 + lane * 4);
  float qx = bf2f(q4.x), qy = bf2f(q4.y), qz = bf2f(q4.z), qw = bf2f(q4.w);
  int beg = rowptr[node], end = rowptr[node + 1];
  float ss = 0.f;
  float a0 = 0.f, a1 = 0.f, a2 = 0.f, a3 = 0.f;
  int i = beg;
  for (; i + 3 < end; i += 4) {
    int2 e0 = epe[i], e1 = epe[i + 1], e2 = epe[i + 2], e3 = epe[i + 3];
    const unsigned short* kp0 = QKV + (size_t)(e0.x & 0x7FFFFFFF) * 768 + 256 + lane * 4;
    const unsigned short* kp1 = QKV + (size_t)(e1.x & 0x7FFFFFFF) * 768 + 256 + lane * 4;
    const unsigned short* kp2 = QKV + (size_t)(e2.x & 0x7FFFFFFF) * 768 + 256 + lane * 4;
    const unsigned short* kp3 = QKV + (size_t)(e3.x & 0x7FFFFFFF) * 768 + 256 + lane * 4;
    ushort4 k0 = *(const ushort4*)kp0, v0 = *(const ushort4*)(kp0 + 256);
    ushort4 k1 = *(const ushort4*)kp1, v1 = *(const ushort4*)(kp1 + 256);
    ushort4 k2 = *(const ushort4*)kp2, v2 = *(const ushort4*)(kp2 + 256);
    ushort4 k3 = *(const ushort4*)kp3, v3 = *(const ushort4*)(kp3 + 256);
    float d0 = qx * bf2f(k0.x) + qy * bf2f(k0.y) + qz * bf2f(k0.z) + qw * bf2f(k0.w);
    float d1 = qx * bf2f(k1.x) + qy * bf2f(k1.y) + qz * bf2f(k1.z) + qw * bf2f(k1.w);
    float d2 = qx * bf2f(k2.x) + qy * bf2f(k2.y) + qz * bf2f(k2.z) + qw * bf2f(k2.w);
    float d3 = qx * bf2f(k3.x) + qy * bf2f(k3.y) + qz * bf2f(k3.z) + qw * bf2f(k3.w);
    d0 += __shfl_xor(d0, 1); d1 += __shfl_xor(d1, 1); d2 += __shfl_xor(d2, 1); d3 += __shfl_xor(d3, 1);
    d0 += __shfl_xor(d0, 2); d1 += __shfl_xor(d1, 2); d2 += __shfl_xor(d2, 2); d3 += __shfl_xor(d3, 2);
    d0 += __shfl_xor(d0, 4); d1 += __shfl_xor(d1, 4); d2 += __shfl_xor(d2, 4); d3 += __shfl_xor(d3, 4);
    float s0 = d0 * 0.17677669529663687f * (float)(((unsigned)e0.x) >> 31) + laml * __int_as_float(e0.y);
    float s1 = d1 * 0.17677669529663687f * (float)(((unsigned)e1.x) >> 31) + laml * __int_as_float(e1.y);
    float s2 = d2 * 0.17677669529663687f * (float)(((unsigned)e2.x) >> 31) + laml * __int_as_float(e2.y);
    float s3 = d3 * 0.17677669529663687f * (float)(((unsigned)e3.x) >> 31) + laml * __int_as_float(e3.y);
    float p0 = __expf(s0), p1 = __expf(s1), p2 = __expf(s2), p3 = __expf(s3);
    ss += (p0 + p1) + (p2 + p3);
    a0 += p0 * bf2f(v0.x) + p1 * bf2f(v1.x) + p2 * bf2f(v2.x) + p3 * bf2f(v3.x);
    a1 += p0 * bf2f(v0.y) + p1 * bf2f(v1.y) + p2 * bf2f(v2.y) + p3 * bf2f(v3.y);
    a2 += p0 * bf2f(v0.z) + p1 * bf2f(v1.z) + p2 * bf2f(v2.z) + p3 * bf2f(v3.z);
    a3 += p0 * bf2f(v0.w) + p1 * bf2f(v1.w) + p2 * bf2f(v2.w) + p3 * bf2f(v3.w);
  }
  for (; i < end; i++) {
    int2 ea = epe[i];
    const unsigned short* kpa = QKV + (size_t)(ea.x & 0x7FFFFFFF) * 768 + 256 + lane * 4;
    ushort4 ka = *(const ushort4*)kpa;
    ushort4 va = *(const ushort4*)(kpa + 256);
    float da = qx * bf2f(ka.x) + qy * bf2f(ka.y) + qz * bf2f(ka.z) + qw * bf2f(ka.w);
    da += __shfl_xor(da, 1);
    da += __shfl_xor(da, 2);
    da += __shfl_xor(da, 4);
    float s0 = da * 0.17677669529663687f * (float)(((unsigned)ea.x) >> 31) + laml * __int_as_float(ea.y);
    float p0 = __expf(s0);
    ss += p0;
    a0 += p0 * bf2f(va.x);
    a1 += p0 * bf2f(va.y);
    a2 += p0 * bf2f(va.z);
    a3 += p0 * bf2f(va.w);
  }
  float inv = 1.f / (ss + 1e-16f);
  ushort4 o;
  o.x = f2bf(a0 * inv); o.y = f2bf(a1 * inv);
  o.z = f2bf(a2 * inv); o.w = f2bf(a3 * inv);
  *(ushort4*)(agg + (size_t)node * DDIM + lane * 4) = o;
}

// ---- standalone LayerNorm (final output only) ----
__global__ __launch_bounds__(256) void ln_kernel(
    const float* __restrict__ X, const float* __restrict__ g,
    const float* __restrict__ b, float* __restrict__ out, int M)
{
  int row = blockIdx.x * (blockDim.x >> 6) + (threadIdx.x >> 6);
  int lane = threadIdx.x & 63;
  if (row >= M) return;
  float4 x = ((const float4*)(X + (size_t)row * DDIM))[lane];
  float s = x.x + x.y + x.z + x.w;
  #pragma unroll
  for (int mk = 1; mk < 64; mk <<= 1) s += __shfl_xor(s, mk);
  float mu = s * (1.f / DDIM);
  float d0 = x.x - mu, d1 = x.y - mu, d2 = x.z - mu, d3 = x.w - mu;
  float vs = d0 * d0 + d1 * d1 + d2 * d2 + d3 * d3;
  #pragma unroll
  for (int mk = 1; mk < 64; mk <<= 1) vs += __shfl_xor(vs, mk);
  float inv = rsqrtf(vs * (1.f / DDIM) + 1e-5f);
  float4 gg = ((const float4*)g)[lane];
  float4 bb = ((const float4*)b)[lane];
  float4 o;
  o.x = d0 * inv * gg.x + bb.x;
  o.y = d1 * inv * gg.y + bb.y;
  o.z = d2 * inv * gg.z + bb.z;
  o.w = d3 * inv * gg.w + bb.w;
  ((float4*)(out + (size_t)row * DDIM))[lane] = o;
}

// ---- host launch ----
extern "C" void kernel_launch(void* const* d_in, const int* in_sizes, int n_in,
                              void* d_out, int out_size, void* d_ws, size_t ws_size,
                              hipStream_t stream) {
  const float* x      = (const float*)d_in[0];
  const int*   ei     = (const int*)d_in[1];
  const int*   scm    = (const int*)d_in[2];
  const float* fcw    = (const float*)d_in[3];
  const float* in_w   = (const float*)d_in[4];
  const float* in_b   = (const float*)d_in[5];
  const float* st_emb = (const float*)d_in[6];
  const float* Wq     = (const float*)d_in[7];
  const float* Wk     = (const float*)d_in[8];
  const float* Wv     = (const float*)d_in[9];
  const float* Wo     = (const float*)d_in[10];
  const float* bo     = (const float*)d_in[11];
  const float* ln1g   = (const float*)d_in[12];
  const float* ln1b   = (const float*)d_in[13];
  const float* ln2g   = (const float*)d_in[14];
  const float* ln2b   = (const float*)d_in[15];
  const float* fw1    = (const float*)d_in[16];
  const float* fb1    = (const float*)d_in[17];
  const float* fw2    = (const float*)d_in[18];
  const float* fb2    = (const float*)d_in[19];
  const float* lam    = (const float*)d_in[20];
  const float* fus_w  = (const float*)d_in[21];
  const float* fus_b  = (const float*)d_in[22];
  const float* outg   = (const float*)d_in[23];
  const float* outb   = (const float*)d_in[24];

  const size_t ND = (size_t)N_NODES * DDIM;   // 5.12M
  const int DD = DDIM * DDIM;                  // 65536
  float* W = (float*)d_ws;
  size_t off = 0;
  auto alloc = [&](size_t n) { float* p = W + off; off += n; return p; };
  // union: f1 bf16 [N,1024] | QKV bf16 [N,768] interleaved
  float* u1 = alloc((size_t)N_NODES * 1024 / 2);
  unsigned short* f1  = (unsigned short*)u1;
  unsigned short* QKV = (unsigned short*)u1;
  unsigned short* aggb    = (unsigned short*)alloc(ND / 2);
  float* base = alloc(ND);
  float* h    = alloc(ND);
  float* out1 = alloc(ND);
  unsigned short* h_bf    = (unsigned short*)alloc(ND / 2);
  unsigned short* out1_bf = (unsigned short*)alloc(ND / 2);
  unsigned short* bfb = (unsigned short*)alloc(1310720);  // 2,621,440 shorts
  unsigned short* wqkvT = bfb;                   // 3 * 196608
  unsigned short* woT   = bfb + 589824;          // 3 * 65536
  unsigned short* fw1T  = bfb + 786432;          // 3 * 262144
  unsigned short* fw2T  = bfb + 1572864;         // 3 * 262144
  unsigned short* fusT  = bfb + 2359296;         // 262144
  int*  rowptr4 = (int*)alloc(4 * (N_NODES + 1) + 4);
  int*  deg4    = (int*)alloc(4 * N_NODES);
  int*  cur4    = (int*)alloc(4 * N_NODES);
  int2* epe4    = (int2*)alloc((size_t)4 * EE * 2);
  float* fus   = (float*)d_out;

  // ---- weights -> bf16 transposed (Wq/Wk/Wv/Wo batched into one dispatch) ----
  transpose_qkvo_kernel<<<dim3(4, 4, 12), 256, 0, stream>>>(Wq, Wk, Wv, Wo, wqkvT, woT);
  transpose_bf16_tiled<<<dim3(16, 4, 3), 256, 0, stream>>>(fw1, fw1T, DDIM, 4 * DDIM, DDIM, 4 * DD, 4 * DD);
  transpose_bf16_tiled<<<dim3(4, 16, 3), 256, 0, stream>>>(fw2, fw2T, 4 * DDIM, DDIM, 4 * DDIM, 4 * DD, 4 * DD);
  transpose_bf16_tiled<<<dim3(4, 16, 1), 256, 0, stream>>>(fus_w, fusT, 4 * DDIM, DDIM, 4 * DDIM, 0, 0);

  // ---- CSR build for ALL 4 stages, once, batched on z ----
  const int eBlocks = (EE + 255) / 256;
  ifill_kernel<<<(8 * N_NODES + 255) / 256, 256, 0, stream>>>(deg4, 0, 8 * N_NODES);  // deg4+cur4
  hist_kernel<<<dim3(eBlocks, 1, 4), 256, 0, stream>>>(ei, deg4);
  scan_kernel<<<dim3(1, 1, 4), 1024, 0, stream>>>(deg4, rowptr4);
  csrfill_kernel<<<dim3(eBlocks, 1, 4), 256, 0, stream>>>(ei, scm, fcw, rowptr4, cur4, epe4);

  // base = x @ in_w + in_b (once)
  dim3 gF32(DDIM / 64, (N_NODES + 63) / 64);
  gemm_f32_kernel<<<gF32, 256, 0, stream>>>(x, in_w, in_b, base, N_NODES, DDIM, FDIM);

  const int lnBlocks = (N_NODES + 3) / 4;
  const int emBlocks = (N_NODES * 64 + 255) / 256;
  dim3 gQKV(6, (N_NODES + 63) / 64);   // 64x128 tiles
  dim3 gFFN1(8, (N_NODES + 63) / 64);
  const int fusedBlocks = (N_NODES + 31) / 32;   // 625

  for (int s = 0; s < SS; s++) {
    const int* rowptr = rowptr4 + s * (N_NODES + 1);
    const int2* epe = epe4 + (size_t)s * EE;

    // h = base + stage_emb[s]  (f32 + bf16)
    add_emb_dual<<<emBlocks, 256, 0, stream>>>(base, st_emb + s * DDIM, h, h_bf);

    for (int l = 0; l < LL; l++) {
      // fused QKV: [N,768] bf16 interleaved
      mfma_gemm64<0><<<gQKV, 256, 0, stream>>>(
          h_bf, wqkvT + (size_t)l * 196608, nullptr, QKV, 768, N_NODES, DDIM, DDIM);

      attn_agg_kernel<<<lnBlocks, 256, 0, stream>>>(QKV, rowptr, epe, lam, l, aggb);

      // Wo + bias + resid(h) + LN1 -> out1 (f32+bf16)
      gemm_ln_kernel<8, 1, 0><<<fusedBlocks, 256, 0, stream>>>(
          aggb, woT + (size_t)l * DD, bo + l * DDIM, h,
          ln1g + l * DDIM, ln1b + l * DDIM, out1, out1_bf, N_NODES, DDIM, 0);

      // FFN1 + gelu -> f1 bf16
      mfma_gemm64<1><<<gFFN1, 256, 0, stream>>>(
          out1_bf, fw1T + (size_t)l * 4 * DD, fb1 + l * 4 * DDIM, f1, 4 * DDIM,
          N_NODES, DDIM, DDIM);

      // FFN2 + bias + resid(out1) + LN2 -> h (f32+bf16)
      gemm_ln_kernel<32, 1, 0><<<fusedBlocks, 256, 0, stream>>>(
          f1, fw2T + (size_t)l * 4 * DD, fb2 + l * DDIM, out1,
          ln2g + l * DDIM, ln2b + l * DDIM, h, h_bf, N_NODES, 4 * DDIM, 0);
    }

    // fusion accumulate into d_out
    if (s == 0)
      gemm_ln_kernel<8, 0, 0><<<fusedBlocks, 256, 0, stream>>>(
          h_bf, fusT, fus_b, nullptr, nullptr, nullptr, fus, nullptr,
          N_NODES, 4 * DDIM, s * DDIM);
    else
      gemm_ln_kernel<8, 0, 1><<<fusedBlocks, 256, 0, stream>>>(
          h_bf, fusT, nullptr, nullptr, nullptr, nullptr, fus, nullptr,
          N_NODES, 4 * DDIM, s * DDIM);
  }

  // final LN in-place on d_out
  ln_kernel<<<lnBlocks, 256, 0, stream>>>(fus, outg, outb, (float*)d_out, N_NODES);
}

// Round 14
// 2482.670 us; speedup vs baseline: 1.1409x; 1.0024x over previous
//
#include <hip/hip_runtime.h>
#include <hip/hip_bf16.h>
#include <math.h>

#define N_NODES 20000
#define FDIM 20
#define DDIM 256
#define HH 8
#define LL 3
#define SS 4
#define EE 320000

typedef __attribute__((ext_vector_type(8))) short bf16x8;
typedef __attribute__((ext_vector_type(8))) unsigned short u16x8;
typedef __attribute__((ext_vector_type(4))) float f32x4;

__device__ inline unsigned short f2bf(float f) {
  unsigned u = __float_as_uint(f);
  unsigned r = u + 0x7FFFu + ((u >> 16) & 1u);
  return (unsigned short)(r >> 16);
}
__device__ inline float bf2f(unsigned short u) {
  return __uint_as_float(((unsigned)u) << 16);
}

// ---- f32 GEMM (x@in_w, K=20): C = A@B + bias (f32 out) ----
__global__ __launch_bounds__(256) void gemm_f32_kernel(
    const float* __restrict__ A, const float* __restrict__ B,
    const float* __restrict__ bias, float* __restrict__ C,
    int M, int Nc, int K)
{
  __shared__ float As[16][65];
  __shared__ float Bs[16][65];
  const int tid = threadIdx.x;
  const int tx = tid & 15, ty = tid >> 4;
  const int row0 = blockIdx.y * 64, col0 = blockIdx.x * 64;
  const int am = tid >> 2, ak = (tid & 3) * 4;
  const int bk = tid >> 4, bc = (tid & 15) * 4;
  float acc[4][4] = {};
  for (int k0 = 0; k0 < K; k0 += 16) {
    float4 av = make_float4(0.f, 0.f, 0.f, 0.f);
    int garow = row0 + am;
    if (garow < M) {
      if (k0 + ak + 3 < K) {
        av = *(const float4*)(A + (size_t)garow * K + k0 + ak);
      } else {
        float t[4];
        #pragma unroll
        for (int j = 0; j < 4; j++)
          t[j] = (k0 + ak + j < K) ? A[(size_t)garow * K + k0 + ak + j] : 0.f;
        av = make_float4(t[0], t[1], t[2], t[3]);
      }
    }
    As[ak + 0][am] = av.x; As[ak + 1][am] = av.y;
    As[ak + 2][am] = av.z; As[ak + 3][am] = av.w;
    float4 bv = make_float4(0.f, 0.f, 0.f, 0.f);
    if (k0 + bk < K)
      bv = *(const float4*)(B + (size_t)(k0 + bk) * Nc + col0 + bc);
    Bs[bk][bc + 0] = bv.x; Bs[bk][bc + 1] = bv.y;
    Bs[bk][bc + 2] = bv.z; Bs[bk][bc + 3] = bv.w;
    __syncthreads();
    #pragma unroll
    for (int kk = 0; kk < 16; kk++) {
      float a[4], b[4];
      #pragma unroll
      for (int i = 0; i < 4; i++) a[i] = As[kk][ty * 4 + i];
      #pragma unroll
      for (int j = 0; j < 4; j++) b[j] = Bs[kk][tx * 4 + j];
      #pragma unroll
      for (int i = 0; i < 4; i++)
        #pragma unroll
        for (int j = 0; j < 4; j++)
          acc[i][j] = fmaf(a[i], b[j], acc[i][j]);
    }
    __syncthreads();
  }
  #pragma unroll
  for (int i = 0; i < 4; i++) {
    int row = row0 + ty * 4 + i;
    if (row >= M) continue;
    int col = col0 + tx * 4;
    float4 v;
    float* vp = &v.x;
    #pragma unroll
    for (int j = 0; j < 4; j++) vp[j] = acc[i][j] + bias[col + j];
    *(float4*)(C + (size_t)row * Nc + col) = v;
  }
}

// ---- bf16 MFMA GEMM, 64x128 tile, 4 waves, BK=32, depth-1 dbuf LDS ----
template<int ACT>
__global__ __launch_bounds__(256) void mfma_gemm64(
    const unsigned short* __restrict__ A, const unsigned short* __restrict__ BT,
    const float* __restrict__ bias, unsigned short* __restrict__ Cb,
    int ldc, int M, int K, int ldb)
{
  __shared__ unsigned short As[2][64][40];
  __shared__ unsigned short Bs[2][128][40];
  const int tid = threadIdx.x, lane = tid & 63, wid = tid >> 6;
  const int wr = (wid >> 1) * 32, wc = (wid & 1) * 64;
  const int row0 = blockIdx.y * 64, col0 = blockIdx.x * 128;
  const int sr = tid >> 2, sc = (tid & 3) * 8;
  const int c15 = lane & 15, g16 = lane >> 4;
  const int KT = K >> 5;
  f32x4 acc[2][4] = {};
  u16x8 areg, breg0, breg1;
  int garow = row0 + sr; if (garow > M - 1) garow = M - 1;
  const unsigned short* Aptr = A + (size_t)garow * K + sc;
  const unsigned short* Bptr0 = BT + (size_t)(col0 + sr) * ldb + sc;
  const unsigned short* Bptr1 = BT + (size_t)(col0 + 64 + sr) * ldb + sc;

  areg = *(const u16x8*)(Aptr);
  breg0 = *(const u16x8*)(Bptr0);
  breg1 = *(const u16x8*)(Bptr1);
  *(u16x8*)&As[0][sr][sc] = areg;
  *(u16x8*)&Bs[0][sr][sc] = breg0;
  *(u16x8*)&Bs[0][64 + sr][sc] = breg1;
  __syncthreads();

  for (int kt = 0; kt < KT; kt++) {
    const int cur = kt & 1;
    if (kt + 1 < KT) {
      int k0 = (kt + 1) << 5;
      areg = *(const u16x8*)(Aptr + k0);
      breg0 = *(const u16x8*)(Bptr0 + k0);
      breg1 = *(const u16x8*)(Bptr1 + k0);
    }
    bf16x8 af[2], bfv[4];
    #pragma unroll
    for (int mi = 0; mi < 2; mi++)
      af[mi] = *(const bf16x8*)&As[cur][wr + mi * 16 + c15][g16 * 8];
    #pragma unroll
    for (int ni = 0; ni < 4; ni++)
      bfv[ni] = *(const bf16x8*)&Bs[cur][wc + ni * 16 + c15][g16 * 8];
    #pragma unroll
    for (int mi = 0; mi < 2; mi++)
      #pragma unroll
      for (int ni = 0; ni < 4; ni++)
        acc[mi][ni] = __builtin_amdgcn_mfma_f32_16x16x32_bf16(af[mi], bfv[ni], acc[mi][ni], 0, 0, 0);
    if (kt + 1 < KT) {
      *(u16x8*)&As[1 - cur][sr][sc] = areg;
      *(u16x8*)&Bs[1 - cur][sr][sc] = breg0;
      *(u16x8*)&Bs[1 - cur][64 + sr][sc] = breg1;
    }
    __syncthreads();
  }
  #pragma unroll
  for (int mi = 0; mi < 2; mi++) {
    #pragma unroll
    for (int ni = 0; ni < 4; ni++) {
      int col = col0 + wc + ni * 16 + c15;
      float bval = bias ? bias[col] : 0.f;
      #pragma unroll
      for (int j = 0; j < 4; j++) {
        int row = row0 + wr + mi * 16 + g16 * 4 + j;
        if (row < M) {
          float t = acc[mi][ni][j] + bval;
          if (ACT == 1) t = 0.5f * t * (1.f + erff(t * 0.7071067811865475f));
          Cb[(size_t)row * ldc + col] = f2bf(t);
        }
      }
    }
  }
}

// ---- fused GEMM (+bias +resid) [+LN], 32x256, BK=32, depth-1 dbuf, 625 blocks ----
template<int KTILES, int DO_LN, int ACCUM>
__global__ __launch_bounds__(256) void gemm_ln_kernel(
    const unsigned short* __restrict__ A, const unsigned short* __restrict__ BT,
    const float* __restrict__ bias, const float* __restrict__ resid,
    const float* __restrict__ gv, const float* __restrict__ bv,
    float* __restrict__ outf, unsigned short* __restrict__ outb,
    int M, int ldb, int bk0)
{
  constexpr int K = KTILES * 32;
  __shared__ unsigned short As[2][32][40];
  __shared__ unsigned short Bs[2][256][40];
  __shared__ float red[32][4][2];
  __shared__ float stats[32][2];
  const int tid = threadIdx.x, lane = tid & 63, w = tid >> 6;
  const int row0 = blockIdx.x * 32;
  const int sr2 = tid >> 3, sc2 = (tid & 7) * 4;
  const int sr = tid >> 2, sc = (tid & 3) * 8;
  const int g16 = lane >> 4, c15 = lane & 15;
  f32x4 acc[2][4] = {};
  ushort4 areg;
  u16x8 breg[4];
  int garow = row0 + sr2; if (garow > M - 1) garow = M - 1;
  const unsigned short* Aptr = A + (size_t)garow * K + sc2;
  const unsigned short* Bptr[4];
  #pragma unroll
  for (int p = 0; p < 4; p++)
    Bptr[p] = BT + (size_t)(p * 64 + sr) * ldb + bk0 + sc;

  areg = *(const ushort4*)(Aptr);
  #pragma unroll
  for (int p = 0; p < 4; p++) breg[p] = *(const u16x8*)(Bptr[p]);
  *(ushort4*)&As[0][sr2][sc2] = areg;
  #pragma unroll
  for (int p = 0; p < 4; p++) *(u16x8*)&Bs[0][p * 64 + sr][sc] = breg[p];
  __syncthreads();

  for (int kt = 0; kt < KTILES; kt++) {
    const int cur = kt & 1;
    if (kt + 1 < KTILES) {
      int k0 = (kt + 1) << 5;
      areg = *(const ushort4*)(Aptr + k0);
      #pragma unroll
      for (int p = 0; p < 4; p++) breg[p] = *(const u16x8*)(Bptr[p] + k0);
    }
    bf16x8 af[2], bfv[4];
    #pragma unroll
    for (int mi = 0; mi < 2; mi++)
      af[mi] = *(const bf16x8*)&As[cur][mi * 16 + c15][g16 * 8];
    #pragma unroll
    for (int ni = 0; ni < 4; ni++)
      bfv[ni] = *(const bf16x8*)&Bs[cur][w * 64 + ni * 16 + c15][g16 * 8];
    #pragma unroll
    for (int mi = 0; mi < 2; mi++)
      #pragma unroll
      for (int ni = 0; ni < 4; ni++)
        acc[mi][ni] = __builtin_amdgcn_mfma_f32_16x16x32_bf16(af[mi], bfv[ni], acc[mi][ni], 0, 0, 0);
    if (kt + 1 < KTILES) {
      *(ushort4*)&As[1 - cur][sr2][sc2] = areg;
      #pragma unroll
      for (int p = 0; p < 4; p++) *(u16x8*)&Bs[1 - cur][p * 64 + sr][sc] = breg[p];
    }
    __syncthreads();
  }
  // epilogue: bias / residual / accum
  #pragma unroll
  for (int mi = 0; mi < 2; mi++)
    #pragma unroll
    for (int ni = 0; ni < 4; ni++) {
      int col = w * 64 + ni * 16 + c15;
      float bval = bias ? bias[col] : 0.f;
      #pragma unroll
      for (int j = 0; j < 4; j++) {
        int row = row0 + mi * 16 + g16 * 4 + j;
        float t = acc[mi][ni][j] + bval;
        if (row < M) {
          if (DO_LN) t += resid[(size_t)row * DDIM + col];
          if (ACCUM) t += outf[(size_t)row * DDIM + col];
        }
        acc[mi][ni][j] = t;
      }
    }
  if (DO_LN) {
    #pragma unroll
    for (int mi = 0; mi < 2; mi++)
      #pragma unroll
      for (int j = 0; j < 4; j++) {
        float s = 0.f, q = 0.f;
        #pragma unroll
        for (int ni = 0; ni < 4; ni++) { float t = acc[mi][ni][j]; s += t; q += t * t; }
        #pragma unroll
        for (int d = 1; d < 16; d <<= 1) { s += __shfl_xor(s, d); q += __shfl_xor(q, d); }
        if (c15 == 0) {
          int r = mi * 16 + g16 * 4 + j;
          red[r][w][0] = s; red[r][w][1] = q;
        }
      }
    __syncthreads();
    if (tid < 32) {
      float s = red[tid][0][0] + red[tid][1][0] + red[tid][2][0] + red[tid][3][0];
      float q = red[tid][0][1] + red[tid][1][1] + red[tid][2][1] + red[tid][3][1];
      float mu = s * (1.f / DDIM);
      float var = q * (1.f / DDIM) - mu * mu;
      stats[tid][0] = mu;
      stats[tid][1] = rsqrtf(var + 1e-5f);
    }
    __syncthreads();
  }
  #pragma unroll
  for (int mi = 0; mi < 2; mi++)
    #pragma unroll
    for (int ni = 0; ni < 4; ni++) {
      int col = w * 64 + ni * 16 + c15;
      #pragma unroll
      for (int j = 0; j < 4; j++) {
        int r = mi * 16 + g16 * 4 + j;
        int row = row0 + r;
        if (row >= M) continue;
        float t = acc[mi][ni][j];
        float o = DO_LN ? (t - stats[r][0]) * stats[r][1] * gv[col] + bv[col] : t;
        outf[(size_t)row * DDIM + col] = o;
        if (DO_LN) outb[(size_t)row * DDIM + col] = f2bf(o);
      }
    }
}

// ---- tiled coalesced transpose f32 -> bf16 (generic, z-batched) ----
__global__ __launch_bounds__(256) void transpose_bf16_tiled(
    const float* __restrict__ W, unsigned short* __restrict__ WT,
    int K, int Nn, int ldo, size_t istr, size_t ostr)
{
  __shared__ unsigned short t[64][65];
  const float* src = W + blockIdx.z * istr;
  unsigned short* dst = WT + blockIdx.z * ostr;
  int tid = threadIdx.x;
  int ty = tid >> 4, tx = tid & 15;
  int k0 = blockIdx.y * 64, n0 = blockIdx.x * 64;
  #pragma unroll
  for (int r = 0; r < 4; r++) {
    int k = k0 + r * 16 + ty;
    float4 v = *(const float4*)(src + (size_t)k * Nn + n0 + tx * 4);
    t[tx * 4 + 0][r * 16 + ty] = f2bf(v.x);
    t[tx * 4 + 1][r * 16 + ty] = f2bf(v.y);
    t[tx * 4 + 2][r * 16 + ty] = f2bf(v.z);
    t[tx * 4 + 3][r * 16 + ty] = f2bf(v.w);
  }
  __syncthreads();
  #pragma unroll
  for (int r = 0; r < 4; r++) {
    int n = r * 16 + ty;
    ushort4 o;
    o.x = t[n][tx * 4 + 0]; o.y = t[n][tx * 4 + 1];
    o.z = t[n][tx * 4 + 2]; o.w = t[n][tx * 4 + 3];
    *(ushort4*)(dst + (size_t)(n0 + n) * ldo + k0 + tx * 4) = o;
  }
}

// ---- batched 256x256 transpose for Wq/Wk/Wv/Wo (z = widx*3 + layer) ----
__global__ __launch_bounds__(256) void transpose_qkvo_kernel(
    const float* __restrict__ Wq, const float* __restrict__ Wk,
    const float* __restrict__ Wv, const float* __restrict__ Wo,
    unsigned short* __restrict__ wqkvT, unsigned short* __restrict__ woT)
{
  __shared__ unsigned short t[64][65];
  const int z = blockIdx.z;
  const int widx = z / 3, lay = z - widx * 3;
  const float* srcs[4] = { Wq, Wk, Wv, Wo };
  const float* src = srcs[widx] + (size_t)lay * 65536;
  unsigned short* dst = (widx < 3)
      ? wqkvT + (size_t)lay * 196608 + (size_t)widx * 65536
      : woT + (size_t)lay * 65536;
  int tid = threadIdx.x;
  int ty = tid >> 4, tx = tid & 15;
  int k0 = blockIdx.y * 64, n0 = blockIdx.x * 64;
  #pragma unroll
  for (int r = 0; r < 4; r++) {
    int k = k0 + r * 16 + ty;
    float4 v = *(const float4*)(src + (size_t)k * DDIM + n0 + tx * 4);
    t[tx * 4 + 0][r * 16 + ty] = f2bf(v.x);
    t[tx * 4 + 1][r * 16 + ty] = f2bf(v.y);
    t[tx * 4 + 2][r * 16 + ty] = f2bf(v.z);
    t[tx * 4 + 3][r * 16 + ty] = f2bf(v.w);
  }
  __syncthreads();
  #pragma unroll
  for (int r = 0; r < 4; r++) {
    int n = r * 16 + ty;
    ushort4 o;
    o.x = t[n][tx * 4 + 0]; o.y = t[n][tx * 4 + 1];
    o.z = t[n][tx * 4 + 2]; o.w = t[n][tx * 4 + 3];
    *(ushort4*)(dst + (size_t)(n0 + n) * DDIM + k0 + tx * 4) = o;
  }
}

// ---- helpers ----
__global__ void ifill_kernel(int* __restrict__ p, int v, int n) {
  int i = blockIdx.x * blockDim.x + threadIdx.x;
  if (i < n) p[i] = v;
}

__global__ void add_emb_dual(const float* __restrict__ base, const float* __restrict__ se,
                             float* __restrict__ h, unsigned short* __restrict__ hb) {
  int i4 = blockIdx.x * blockDim.x + threadIdx.x;
  if (i4 >= N_NODES * 64) return;
  float4 v = ((const float4*)base)[i4];
  float4 e = ((const float4*)se)[i4 & 63];
  v.x += e.x; v.y += e.y; v.z += e.z; v.w += e.w;
  ((float4*)h)[i4] = v;
  ushort4 o;
  o.x = f2bf(v.x); o.y = f2bf(v.y); o.z = f2bf(v.z); o.w = f2bf(v.w);
  ((ushort4*)hb)[i4] = o;
}

// ---- CSR build, batched over 4 stages via blockIdx.z ----
// Packed edge record (4B): bits 0-14 src, bit 15 sc, bits 16-31 fcw (bf16).
__global__ void hist_kernel(const int* __restrict__ ei, int* __restrict__ deg4) {
  int z = blockIdx.z;
  const int* dst = ei + (size_t)z * 2 * EE + EE;
  int* deg = deg4 + z * N_NODES;
  int e = blockIdx.x * blockDim.x + threadIdx.x;
  if (e < EE) atomicAdd(&deg[dst[e]], 1);
}

__global__ __launch_bounds__(1024) void scan_kernel(const int* __restrict__ deg4,
                                                    int* __restrict__ rowptr4) {
  int z = blockIdx.z;
  const int* deg = deg4 + z * N_NODES;
  int* rowptr = rowptr4 + z * (N_NODES + 1);
  __shared__ int part[1024];
  const int t = threadIdx.x;
  const int CH = (N_NODES + 1023) / 1024;
  int base = t * CH, s = 0;
  for (int i = 0; i < CH; i++) {
    int idx = base + i;
    if (idx < N_NODES) s += deg[idx];
  }
  part[t] = s;
  __syncthreads();
  for (int off = 1; off < 1024; off <<= 1) {
    int v = (t >= off) ? part[t - off] : 0;
    __syncthreads();
    part[t] += v;
    __syncthreads();
  }
  int run = (t == 0) ? 0 : part[t - 1];
  for (int i = 0; i < CH; i++) {
    int idx = base + i;
    if (idx < N_NODES) { rowptr[idx] = run; run += deg[idx]; }
  }
  if (t == 1023) rowptr[N_NODES] = run;
}

__global__ void csrfill_kernel(const int* __restrict__ ei,
                               const int* __restrict__ scm, const float* __restrict__ fcw,
                               const int* __restrict__ rowptr4, int* __restrict__ cur4,
                               int* __restrict__ epe4) {
  int z = blockIdx.z;
  const int* src = ei + (size_t)z * 2 * EE;
  const int* dst = src + EE;
  const int* sc = scm + (size_t)z * EE;
  const float* fw = fcw + (size_t)z * EE;
  const int* rowptr = rowptr4 + z * (N_NODES + 1);
  int* cur = cur4 + z * N_NODES;
  int* epe = epe4 + (size_t)z * EE;
  int e = blockIdx.x * blockDim.x + threadIdx.x;
  if (e >= EE) return;
  int d = dst[e];
  int slot = rowptr[d] + atomicAdd(&cur[d], 1);
  epe[slot] = src[e] | (sc[e] << 15) | ((int)f2bf(fw[e]) << 16);
}

// ---- fused edge attention + aggregation: wave-per-node, no online max ----
// softmax is shift-invariant; scores bounded (LN'd bf16 inputs) so raw
// expf is safe in f32 -> no loop-carried rescale chain.
__global__ __launch_bounds__(256) void attn_agg_kernel(
    const unsigned short* __restrict__ QKV,
    const int* __restrict__ rowptr, const int* __restrict__ epe,
    const float* __restrict__ lam, int l,
    unsigned short* __restrict__ agg)
{
  int node = blockIdx.x * 4 + (threadIdx.x >> 6);
  int lane = threadIdx.x & 63;
  if (node >= N_NODES) return;
  const float laml = lam[l];
  ushort4 q4 = *(const ushort4*)(QKV + (size_t)node * 768 + lane * 4);
  float qx = bf2f(q4.x), qy = bf2f(q4.y), qz = bf2f(q4.z), qw = bf2f(q4.w);
  int beg = rowptr[node], end = rowptr[node + 1];
  float ss = 0.f;
  float a0 = 0.f, a1 = 0.f, a2 = 0.f, a3 = 0.f;
  int i = beg;
  for (; i + 3 < end; i += 4) {
    int e0 = epe[i], e1 = epe[i + 1], e2 = epe[i + 2], e3 = epe[i + 3];
    const unsigned short* kp0 = QKV + (size_t)(e0 & 0x7FFF) * 768 + 256 + lane * 4;
    const unsigned short* kp1 = QKV + (size_t)(e1 & 0x7FFF) * 768 + 256 + lane * 4;
    const unsigned short* kp2 = QKV + (size_t)(e2 & 0x7FFF) * 768 + 256 + lane * 4;
    const unsigned short* kp3 = QKV + (size_t)(e3 & 0x7FFF) * 768 + 256 + lane * 4;
    ushort4 k0 = *(const ushort4*)kp0, v0 = *(const ushort4*)(kp0 + 256);
    ushort4 k1 = *(const ushort4*)kp1, v1 = *(const ushort4*)(kp1 + 256);
    ushort4 k2 = *(const ushort4*)kp2, v2 = *(const ushort4*)(kp2 + 256);
    ushort4 k3 = *(const ushort4*)kp3, v3 = *(const ushort4*)(kp3 + 256);
    float d0 = qx * bf2f(k0.x) + qy * bf2f(k0.y) + qz * bf2f(k0.z) + qw * bf2f(k0.w);
    float d1 = qx * bf2f(k1.x) + qy * bf2f(k1.y) + qz * bf2f(k1.z) + qw * bf2f(k1.w);
    float d2 = qx * bf2f(k2.x) + qy * bf2f(k2.y) + qz * bf2f(k2.z) + qw * bf2f(k2.w);
    float d3 = qx * bf2f(k3.x) + qy * bf2f(k3.y) + qz * bf2f(k3.z) + qw * bf2f(k3.w);
    d0 += __shfl_xor(d0, 1); d1 += __shfl_xor(d1, 1); d2 += __shfl_xor(d2, 1); d3 += __shfl_xor(d3, 1);
    d0 += __shfl_xor(d0, 2); d1 += __shfl_xor(d1, 2); d2 += __shfl_xor(d2, 2); d3 += __shfl_xor(d3, 2);
    d0 += __shfl_xor(d0, 4); d1 += __shfl_xor(d1, 4); d2 += __shfl_xor(d2, 4); d3 += __shfl_xor(d3, 4);
    float s0 = d0 * 0.17677669529663687f * (float)((e0 >> 15) & 1) + laml * bf2f((unsigned short)((unsigned)e0 >> 16));
    float s1 = d1 * 0.17677669529663687f * (float)((e1 >> 15) & 1) + laml * bf2f((unsigned short)((unsigned)e1 >> 16));
    float s2 = d2 * 0.17677669529663687f * (float)((e2 >> 15) & 1) + laml * bf2f((unsigned short)((unsigned)e2 >> 16));
    float s3 = d3 * 0.17677669529663687f * (float)((e3 >> 15) & 1) + laml * bf2f((unsigned short)((unsigned)e3 >> 16));
    float p0 = __expf(s0), p1 = __expf(s1), p2 = __expf(s2), p3 = __expf(s3);
    ss += (p0 + p1) + (p2 + p3);
    a0 += p0 * bf2f(v0.x) + p1 * bf2f(v1.x) + p2 * bf2f(v2.x) + p3 * bf2f(v3.x);
    a1 += p0 * bf2f(v0.y) + p1 * bf2f(v1.y) + p2 * bf2f(v2.y) + p3 * bf2f(v3.y);
    a2 += p0 * bf2f(v0.z) + p1 * bf2f(v1.z) + p2 * bf2f(v2.z) + p3 * bf2f(v3.z);
    a3 += p0 * bf2f(v0.w) + p1 * bf2f(v1.w) + p2 * bf2f(v2.w) + p3 * bf2f(v3.w);
  }
  for (; i < end; i++) {
    int ea = epe[i];
    const unsigned short* kpa = QKV + (size_t)(ea & 0x7FFF) * 768 + 256 + lane * 4;
    ushort4 ka = *(const ushort4*)kpa;
    ushort4 va = *(const ushort4*)(kpa + 256);
    float da = qx * bf2f(ka.x) + qy * bf2f(ka.y) + qz * bf2f(ka.z) + qw * bf2f(ka.w);
    da += __shfl_xor(da, 1);
    da += __shfl_xor(da, 2);
    da += __shfl_xor(da, 4);
    float s0 = da * 0.17677669529663687f * (float)((ea >> 15) & 1) + laml * bf2f((unsigned short)((unsigned)ea >> 16));
    float p0 = __expf(s0);
    ss += p0;
    a0 += p0 * bf2f(va.x);
    a1 += p0 * bf2f(va.y);
    a2 += p0 * bf2f(va.z);
    a3 += p0 * bf2f(va.w);
  }
  float inv = 1.f / (ss + 1e-16f);
  ushort4 o;
  o.x = f2bf(a0 * inv); o.y = f2bf(a1 * inv);
  o.z = f2bf(a2 * inv); o.w = f2bf(a3 * inv);
  *(ushort4*)(agg + (size_t)node * DDIM + lane * 4) = o;
}

// ---- standalone LayerNorm (final output only) ----
__global__ __launch_bounds__(256) void ln_kernel(
    const float* __restrict__ X, const float* __restrict__ g,
    const float* __restrict__ b, float* __restrict__ out, int M)
{
  int row = blockIdx.x * (blockDim.x >> 6) + (threadIdx.x >> 6);
  int lane = threadIdx.x & 63;
  if (row >= M) return;
  float4 x = ((const float4*)(X + (size_t)row * DDIM))[lane];
  float s = x.x + x.y + x.z + x.w;
  #pragma unroll
  for (int mk = 1; mk < 64; mk <<= 1) s += __shfl_xor(s, mk);
  float mu = s * (1.f / DDIM);
  float d0 = x.x - mu, d1 = x.y - mu, d2 = x.z - mu, d3 = x.w - mu;
  float vs = d0 * d0 + d1 * d1 + d2 * d2 + d3 * d3;
  #pragma unroll
  for (int mk = 1; mk < 64; mk <<= 1) vs += __shfl_xor(vs, mk);
  float inv = rsqrtf(vs * (1.f / DDIM) + 1e-5f);
  float4 gg = ((const float4*)g)[lane];
  float4 bb = ((const float4*)b)[lane];
  float4 o;
  o.x = d0 * inv * gg.x + bb.x;
  o.y = d1 * inv * gg.y + bb.y;
  o.z = d2 * inv * gg.z + bb.z;
  o.w = d3 * inv * gg.w + bb.w;
  ((float4*)(out + (size_t)row * DDIM))[lane] = o;
}

// ---- host launch ----
extern "C" void kernel_launch(void* const* d_in, const int* in_sizes, int n_in,
                              void* d_out, int out_size, void* d_ws, size_t ws_size,
                              hipStream_t stream) {
  const float* x      = (const float*)d_in[0];
  const int*   ei     = (const int*)d_in[1];
  const int*   scm    = (const int*)d_in[2];
  const float* fcw    = (const float*)d_in[3];
  const float* in_w   = (const float*)d_in[4];
  const float* in_b   = (const float*)d_in[5];
  const float* st_emb = (const float*)d_in[6];
  const float* Wq     = (const float*)d_in[7];
  const float* Wk     = (const float*)d_in[8];
  const float* Wv     = (const float*)d_in[9];
  const float* Wo     = (const float*)d_in[10];
  const float* bo     = (const float*)d_in[11];
  const float* ln1g   = (const float*)d_in[12];
  const float* ln1b   = (const float*)d_in[13];
  const float* ln2g   = (const float*)d_in[14];
  const float* ln2b   = (const float*)d_in[15];
  const float* fw1    = (const float*)d_in[16];
  const float* fb1    = (const float*)d_in[17];
  const float* fw2    = (const float*)d_in[18];
  const float* fb2    = (const float*)d_in[19];
  const float* lam    = (const float*)d_in[20];
  const float* fus_w  = (const float*)d_in[21];
  const float* fus_b  = (const float*)d_in[22];
  const float* outg   = (const float*)d_in[23];
  const float* outb   = (const float*)d_in[24];

  const size_t ND = (size_t)N_NODES * DDIM;   // 5.12M
  const int DD = DDIM * DDIM;                  // 65536
  float* W = (float*)d_ws;
  size_t off = 0;
  auto alloc = [&](size_t n) { float* p = W + off; off += n; return p; };
  // union: f1 bf16 [N,1024] | QKV bf16 [N,768] interleaved
  float* u1 = alloc((size_t)N_NODES * 1024 / 2);
  unsigned short* f1  = (unsigned short*)u1;
  unsigned short* QKV = (unsigned short*)u1;
  unsigned short* aggb    = (unsigned short*)alloc(ND / 2);
  float* base = alloc(ND);
  float* h    = alloc(ND);
  float* out1 = alloc(ND);
  unsigned short* h_bf    = (unsigned short*)alloc(ND / 2);
  unsigned short* out1_bf = (unsigned short*)alloc(ND / 2);
  unsigned short* bfb = (unsigned short*)alloc(1310720);  // 2,621,440 shorts
  unsigned short* wqkvT = bfb;                   // 3 * 196608
  unsigned short* woT   = bfb + 589824;          // 3 * 65536
  unsigned short* fw1T  = bfb + 786432;          // 3 * 262144
  unsigned short* fw2T  = bfb + 1572864;         // 3 * 262144
  unsigned short* fusT  = bfb + 2359296;         // 262144
  int*  rowptr4 = (int*)alloc(4 * (N_NODES + 1) + 4);
  int*  deg4    = (int*)alloc(4 * N_NODES);
  int*  cur4    = (int*)alloc(4 * N_NODES);
  int*  epe4    = (int*)alloc((size_t)4 * EE);   // packed 4B records
  float* fus   = (float*)d_out;

  // ---- weights -> bf16 transposed (Wq/Wk/Wv/Wo batched into one dispatch) ----
  transpose_qkvo_kernel<<<dim3(4, 4, 12), 256, 0, stream>>>(Wq, Wk, Wv, Wo, wqkvT, woT);
  transpose_bf16_tiled<<<dim3(16, 4, 3), 256, 0, stream>>>(fw1, fw1T, DDIM, 4 * DDIM, DDIM, 4 * DD, 4 * DD);
  transpose_bf16_tiled<<<dim3(4, 16, 3), 256, 0, stream>>>(fw2, fw2T, 4 * DDIM, DDIM, 4 * DDIM, 4 * DD, 4 * DD);
  transpose_bf16_tiled<<<dim3(4, 16, 1), 256, 0, stream>>>(fus_w, fusT, 4 * DDIM, DDIM, 4 * DDIM, 0, 0);

  // ---- CSR build for ALL 4 stages, once, batched on z ----
  const int eBlocks = (EE + 255) / 256;
  ifill_kernel<<<(8 * N_NODES + 255) / 256, 256, 0, stream>>>(deg4, 0, 8 * N_NODES);  // deg4+cur4
  hist_kernel<<<dim3(eBlocks, 1, 4), 256, 0, stream>>>(ei, deg4);
  scan_kernel<<<dim3(1, 1, 4), 1024, 0, stream>>>(deg4, rowptr4);
  csrfill_kernel<<<dim3(eBlocks, 1, 4), 256, 0, stream>>>(ei, scm, fcw, rowptr4, cur4, epe4);

  // base = x @ in_w + in_b (once)
  dim3 gF32(DDIM / 64, (N_NODES + 63) / 64);
  gemm_f32_kernel<<<gF32, 256, 0, stream>>>(x, in_w, in_b, base, N_NODES, DDIM, FDIM);

  const int lnBlocks = (N_NODES + 3) / 4;
  const int emBlocks = (N_NODES * 64 + 255) / 256;
  dim3 gQKV(6, (N_NODES + 63) / 64);   // 64x128 tiles
  dim3 gFFN1(8, (N_NODES + 63) / 64);
  const int fusedBlocks = (N_NODES + 31) / 32;   // 625

  for (int s = 0; s < SS; s++) {
    const int* rowptr = rowptr4 + s * (N_NODES + 1);
    const int* epe = epe4 + (size_t)s * EE;

    // h = base + stage_emb[s]  (f32 + bf16)
    add_emb_dual<<<emBlocks, 256, 0, stream>>>(base, st_emb + s * DDIM, h, h_bf);

    for (int l = 0; l < LL; l++) {
      // fused QKV: [N,768] bf16 interleaved
      mfma_gemm64<0><<<gQKV, 256, 0, stream>>>(
          h_bf, wqkvT + (size_t)l * 196608, nullptr, QKV, 768, N_NODES, DDIM, DDIM);

      attn_agg_kernel<<<lnBlocks, 256, 0, stream>>>(QKV, rowptr, epe, lam, l, aggb);

      // Wo + bias + resid(h) + LN1 -> out1 (f32+bf16)
      gemm_ln_kernel<8, 1, 0><<<fusedBlocks, 256, 0, stream>>>(
          aggb, woT + (size_t)l * DD, bo + l * DDIM, h,
          ln1g + l * DDIM, ln1b + l * DDIM, out1, out1_bf, N_NODES, DDIM, 0);

      // FFN1 + gelu -> f1 bf16
      mfma_gemm64<1><<<gFFN1, 256, 0, stream>>>(
          out1_bf, fw1T + (size_t)l * 4 * DD, fb1 + l * 4 * DDIM, f1, 4 * DDIM,
          N_NODES, DDIM, DDIM);

      // FFN2 + bias + resid(out1) + LN2 -> h (f32+bf16)
      gemm_ln_kernel<32, 1, 0><<<fusedBlocks, 256, 0, stream>>>(
          f1, fw2T + (size_t)l * 4 * DD, fb2 + l * DDIM, out1,
          ln2g + l * DDIM, ln2b + l * DDIM, h, h_bf, N_NODES, 4 * DDIM, 0);
    }

    // fusion accumulate into d_out
    if (s == 0)
      gemm_ln_kernel<8, 0, 0><<<fusedBlocks, 256, 0, stream>>>(
          h_bf, fusT, fus_b, nullptr, nullptr, nullptr, fus, nullptr,
          N_NODES, 4 * DDIM, s * DDIM);
    else
      gemm_ln_kernel<8, 0, 1><<<fusedBlocks, 256, 0, stream>>>(
          h_bf, fusT, nullptr, nullptr, nullptr, nullptr, fus, nullptr,
          N_NODES, 4 * DDIM, s * DDIM);
  }

  // final LN in-place on d_out
  ln_kernel<<<lnBlocks, 256, 0, stream>>>(fus, outg, outb, (float*)d_out, N_NODES);
}